// Round 1
// baseline (1039.923 us; speedup 1.0000x reference)
//
#include <hip/hip_runtime.h>
#include <math.h>

#define NEG_SLOPE 0.2f

constexpr int NN   = 50000;   // nodes
constexpr int NE   = 400000;  // edges
constexpr int NR   = 500;     // relations
constexpr int INF_ = 128;     // input feat
constexpr int HIDC = 64;      // layer1 per-head channels
constexpr int NH   = 4;       // heads
constexpr int OUTC = 128;     // layer2 per-head channels

// ---------------- simple f32 tiled GEMM: C[M x Nc] = A[M x K] @ B[K x Nc] + bias ----
// C row stride = ldc, column offset = coff (so we can pack [xl | xr] side by side)
__global__ __launch_bounds__(256) void gemm_f32(
    const float* __restrict__ A, const float* __restrict__ B,
    const float* __restrict__ bias, float* __restrict__ C,
    int M, int Nc, int K, int ldc, int coff)
{
    __shared__ float As[64][17];
    __shared__ float Bs[16][65];
    int tid = threadIdx.x;
    int tx = tid & 15, ty = tid >> 4;
    int rowBase = blockIdx.y * 64;
    int colBase = blockIdx.x * 64;
    float acc[4][4] = {};
    for (int k0 = 0; k0 < K; k0 += 16) {
        #pragma unroll
        for (int i = 0; i < 4; ++i) {
            int idx = tid + i * 256;
            int r = idx >> 4, k = idx & 15;
            int gr = rowBase + r;
            As[r][k] = (gr < M) ? A[(size_t)gr * K + k0 + k] : 0.f;
        }
        #pragma unroll
        for (int i = 0; i < 4; ++i) {
            int idx = tid + i * 256;
            int k = idx >> 6, c = idx & 63;
            Bs[k][c] = B[(size_t)(k0 + k) * Nc + colBase + c];
        }
        __syncthreads();
        #pragma unroll
        for (int kk = 0; kk < 16; ++kk) {
            float a[4], b[4];
            #pragma unroll
            for (int i = 0; i < 4; ++i) a[i] = As[ty * 4 + i][kk];
            #pragma unroll
            for (int j = 0; j < 4; ++j) b[j] = Bs[kk][tx * 4 + j];
            #pragma unroll
            for (int i = 0; i < 4; ++i)
                #pragma unroll
                for (int j = 0; j < 4; ++j)
                    acc[i][j] += a[i] * b[j];
        }
        __syncthreads();
    }
    #pragma unroll
    for (int i = 0; i < 4; ++i) {
        int gr = rowBase + ty * 4 + i;
        if (gr >= M) continue;
        #pragma unroll
        for (int j = 0; j < 4; ++j) {
            int gc = colBase + tx * 4 + j;
            float v = acc[i][j] + (bias ? bias[gc] : 0.f);
            C[(size_t)gr * ldc + coff + gc] = v;
        }
    }
}

// ---------------- CSR build ----------------
__global__ void zero_ints(int* __restrict__ p, int n)
{
    int i = blockIdx.x * blockDim.x + threadIdx.x;
    if (i < n) p[i] = 0;
}

__global__ void count_deg(const int* __restrict__ dst, int* __restrict__ deg, int E)
{
    int i = blockIdx.x * blockDim.x + threadIdx.x;
    if (i < E) atomicAdd(&deg[dst[i]], 1);
}

__global__ __launch_bounds__(256) void scan_block_sums(
    const int* __restrict__ deg, int* __restrict__ bsum, int n)
{
    __shared__ int s[256];
    int i = blockIdx.x * 256 + threadIdx.x;
    s[threadIdx.x] = (i < n) ? deg[i] : 0;
    __syncthreads();
    for (int o = 128; o > 0; o >>= 1) {
        if (threadIdx.x < o) s[threadIdx.x] += s[threadIdx.x + o];
        __syncthreads();
    }
    if (threadIdx.x == 0) bsum[blockIdx.x] = s[0];
}

__global__ __launch_bounds__(256) void scan_bsums(
    const int* __restrict__ bsum, int* __restrict__ boff, int nb)
{
    __shared__ int s[256];
    int v = (threadIdx.x < nb) ? bsum[threadIdx.x] : 0;
    s[threadIdx.x] = v;
    __syncthreads();
    for (int o = 1; o < 256; o <<= 1) {
        int t = (threadIdx.x >= o) ? s[threadIdx.x - o] : 0;
        __syncthreads();
        s[threadIdx.x] += t;
        __syncthreads();
    }
    if (threadIdx.x < nb) boff[threadIdx.x] = s[threadIdx.x] - v; // exclusive
}

__global__ __launch_bounds__(256) void scan_final(
    const int* __restrict__ deg, const int* __restrict__ boff,
    int* __restrict__ offsets, int n)
{
    __shared__ int s[256];
    int i = blockIdx.x * 256 + threadIdx.x;
    int v = (i < n) ? deg[i] : 0;
    s[threadIdx.x] = v;
    __syncthreads();
    for (int o = 1; o < 256; o <<= 1) {
        int t = (threadIdx.x >= o) ? s[threadIdx.x - o] : 0;
        __syncthreads();
        s[threadIdx.x] += t;
        __syncthreads();
    }
    int incl = s[threadIdx.x];
    int excl = incl - v;
    if (i < n) offsets[i] = boff[blockIdx.x] + excl;
    if (i == n - 1) offsets[n] = boff[blockIdx.x] + incl;
}

__global__ void fill_adj(const int* __restrict__ src, const int* __restrict__ rel,
                         const int* __restrict__ dst, const int* __restrict__ offsets,
                         int* __restrict__ cursor,
                         int* __restrict__ adj_src, int* __restrict__ adj_rel, int E)
{
    int e = blockIdx.x * blockDim.x + threadIdx.x;
    if (e < E) {
        int d = dst[e];
        int p = atomicAdd(&cursor[d], 1);
        int slot = offsets[d] + p;
        adj_src[slot] = src[e];
        adj_rel[slot] = rel[e];
    }
}

// ---------------- fused per-node GATv2 attention ----------------
// One wave per node. Channels laid out [head][c], head = lane>>4.
// CPH = per-head channels (64 or 128); VPL = floats per lane (4 or 8).
__device__ __forceinline__ float lrelu(float x) { return x > 0.f ? x : NEG_SLOPE * x; }

template <int CPH, bool CONCAT>
__global__ __launch_bounds__(256) void gat_node(
    const float* __restrict__ xlr,      // [n][2*HC]: cols [0,HC)=xl, [HC,2HC)=xr
    const float* __restrict__ erel,     // [NR][HC] precomputed relations@We
    const int* __restrict__ adj_src, const int* __restrict__ adj_rel,
    const int* __restrict__ offsets,
    const float* __restrict__ att,      // [HC] flat (h*CPH+c)
    const float* __restrict__ bias,     // CONCAT ? [HC] : [CPH]
    float* __restrict__ out, int n)
{
    constexpr int HC  = NH * CPH;
    constexpr int VPL = HC / 64;
    int lane = threadIdx.x & 63;
    int wave = threadIdx.x >> 6;
    int v = blockIdx.x * 4 + wave;
    if (v >= n) return;

    const float* xlrow = xlr + (size_t)v * (2 * HC) + lane * VPL;
    const float* xrrow = xlrow + HC;
    float xr_v[VPL], xl_v[VPL], attv[VPL], acc[VPL];
    #pragma unroll
    for (int j = 0; j < VPL; j += 4) {
        *(float4*)&xl_v[j] = *(const float4*)&xlrow[j];
        *(float4*)&xr_v[j] = *(const float4*)&xrrow[j];
        *(float4*)&attv[j] = *(const float4*)&att[lane * VPL + j];
    }

    // self loop (e = 0)
    float part = 0.f;
    #pragma unroll
    for (int j = 0; j < VPL; ++j) part += lrelu(xl_v[j] + xr_v[j]) * attv[j];
    part += __shfl_xor(part, 1);
    part += __shfl_xor(part, 2);
    part += __shfl_xor(part, 4);
    part += __shfl_xor(part, 8);
    float m_run = part, l_run = 1.f;
    #pragma unroll
    for (int j = 0; j < VPL; ++j) acc[j] = xl_v[j];

    int beg = offsets[v], end = offsets[v + 1];
    for (int idx = beg; idx < end; ++idx) {
        int s = adj_src[idx], r = adj_rel[idx];
        const float* xls = xlr + (size_t)s * (2 * HC) + lane * VPL;
        const float* er  = erel + (size_t)r * HC + lane * VPL;
        float xv[VPL], ev[VPL];
        #pragma unroll
        for (int j = 0; j < VPL; j += 4) {
            *(float4*)&xv[j] = *(const float4*)&xls[j];
            *(float4*)&ev[j] = *(const float4*)&er[j];
        }
        float p2 = 0.f;
        #pragma unroll
        for (int j = 0; j < VPL; ++j) p2 += lrelu(xv[j] + xr_v[j] + ev[j]) * attv[j];
        p2 += __shfl_xor(p2, 1);
        p2 += __shfl_xor(p2, 2);
        p2 += __shfl_xor(p2, 4);
        p2 += __shfl_xor(p2, 8);
        float mn = fmaxf(m_run, p2);
        float sc = expf(m_run - mn);
        float p  = expf(p2 - mn);
        l_run = l_run * sc + p;
        #pragma unroll
        for (int j = 0; j < VPL; ++j) acc[j] = acc[j] * sc + p * xv[j];
        m_run = mn;
    }

    float inv = 1.f / l_run;
    if (CONCAT) {
        #pragma unroll
        for (int j = 0; j < VPL; ++j)
            out[(size_t)v * HC + lane * VPL + j] = acc[j] * inv + bias[lane * VPL + j];
    } else {
        // mean over heads: lanes {i, i^16, i^32, i^48} hold same within-head offset
        float t[VPL];
        #pragma unroll
        for (int j = 0; j < VPL; ++j) {
            t[j] = acc[j] * inv;
            t[j] += __shfl_xor(t[j], 16);
            t[j] += __shfl_xor(t[j], 32);
        }
        if (lane < 16) {
            #pragma unroll
            for (int j = 0; j < VPL; ++j)
                out[(size_t)v * CPH + lane * VPL + j] = 0.25f * t[j] + bias[lane * VPL + j];
        }
    }
}

// ---------------- host launcher ----------------
extern "C" void kernel_launch(void* const* d_in, const int* in_sizes, int n_in,
                              void* d_out, int out_size, void* d_ws, size_t ws_size,
                              hipStream_t stream)
{
    const float* x         = (const float*)d_in[0];
    const int*   ei        = (const int*)d_in[1];
    const float* relations = (const float*)d_in[2];
    const float* Wl1  = (const float*)d_in[3];
    const float* bl1  = (const float*)d_in[4];
    const float* Wr1  = (const float*)d_in[5];
    const float* br1  = (const float*)d_in[6];
    const float* We1  = (const float*)d_in[7];
    const float* att1 = (const float*)d_in[8];
    const float* bias1= (const float*)d_in[9];
    const float* Wl2  = (const float*)d_in[10];
    const float* bl2  = (const float*)d_in[11];
    const float* Wr2  = (const float*)d_in[12];
    const float* br2  = (const float*)d_in[13];
    const float* We2  = (const float*)d_in[14];
    const float* att2 = (const float*)d_in[15];
    const float* bias2= (const float*)d_in[16];
    float* out = (float*)d_out;

    const int* src = ei;
    const int* rel = ei + NE;
    const int* dst = ei + 2 * NE;

    // workspace layout (xlr1 shares the xlr2 region; xlr1 dead before xlr2 written)
    float* xlrBig = (float*)d_ws;                       // 50000*1024 f
    float* h      = xlrBig + (size_t)NN * 1024;         // 50000*256 f
    float* erel1  = h + (size_t)NN * 256;               // 500*256 f
    float* erel2  = erel1 + (size_t)NR * 256;           // 500*512 f
    int*   ibuf   = (int*)(erel2 + (size_t)NR * 512);
    int* deg     = ibuf;
    int* offsets = deg + NN;          // NN+1
    int* cursor  = offsets + NN + 1;
    int* bsum    = cursor + NN;       // 256
    int* boff    = bsum + 256;        // 256
    int* adj_src = boff + 256;        // NE
    int* adj_rel = adj_src + NE;      // NE

    const int NB = (NN + 255) / 256;  // 196
    const int EB = (NE + 255) / 256;

    // --- CSR by destination ---
    zero_ints<<<NB, 256, 0, stream>>>(deg, NN);
    zero_ints<<<NB, 256, 0, stream>>>(cursor, NN);
    count_deg<<<EB, 256, 0, stream>>>(dst, deg, NE);
    scan_block_sums<<<NB, 256, 0, stream>>>(deg, bsum, NN);
    scan_bsums<<<1, 256, 0, stream>>>(bsum, boff, NB);
    scan_final<<<NB, 256, 0, stream>>>(deg, boff, offsets, NN);
    fill_adj<<<EB, 256, 0, stream>>>(src, rel, dst, offsets, cursor, adj_src, adj_rel, NE);

    // --- relation edge-embedding tables ---
    gemm_f32<<<dim3(4, (NR + 63) / 64), 256, 0, stream>>>(relations, We1, nullptr, erel1,
                                                          NR, 256, INF_, 256, 0);
    gemm_f32<<<dim3(8, (NR + 63) / 64), 256, 0, stream>>>(relations, We2, nullptr, erel2,
                                                          NR, 512, INF_, 512, 0);

    // --- layer 1 transforms: xlr1 = [x@Wl1+bl1 | x@Wr1+br1], stride 512 ---
    const int MB = (NN + 63) / 64;    // 782
    gemm_f32<<<dim3(4, MB), 256, 0, stream>>>(x, Wl1, bl1, xlrBig, NN, 256, INF_, 512, 0);
    gemm_f32<<<dim3(4, MB), 256, 0, stream>>>(x, Wr1, br1, xlrBig, NN, 256, INF_, 512, 256);

    // --- layer 1 attention -> h [NN][256] ---
    gat_node<HIDC, true><<<(NN + 3) / 4, 256, 0, stream>>>(
        xlrBig, erel1, adj_src, adj_rel, offsets, att1, bias1, h, NN);

    // --- layer 2 transforms: xlr2 = [h@Wl2+bl2 | h@Wr2+br2], stride 1024 (reuses region) ---
    gemm_f32<<<dim3(8, MB), 256, 0, stream>>>(h, Wl2, bl2, xlrBig, NN, 512, 256, 1024, 0);
    gemm_f32<<<dim3(8, MB), 256, 0, stream>>>(h, Wr2, br2, xlrBig, NN, 512, 256, 1024, 512);

    // --- layer 2 attention (mean over heads) -> out [NN][128] ---
    gat_node<OUTC, false><<<(NN + 3) / 4, 256, 0, stream>>>(
        xlrBig, erel2, adj_src, adj_rel, offsets, att2, bias2, out, NN);
}

// Round 2
// 473.012 us; speedup vs baseline: 2.1985x; 2.1985x over previous
//
#include <hip/hip_runtime.h>
#include <math.h>

#define NEG_SLOPE 0.2f

constexpr int NN   = 50000;   // nodes
constexpr int NE   = 400000;  // edges
constexpr int NR   = 500;     // relations
constexpr int INF_ = 128;     // input feat
constexpr int HIDC = 64;      // layer1 per-head channels
constexpr int NH   = 4;       // heads
constexpr int OUTC = 128;     // layer2 per-head channels
constexpr int MPAD = 50048;   // 391 * 128

typedef __attribute__((ext_vector_type(8))) short short8;
typedef __attribute__((ext_vector_type(4))) float f32x4;

__device__ __forceinline__ unsigned short f2bf(float f) {
    unsigned u = __float_as_uint(f);
    u += 0x7FFF + ((u >> 16) & 1);   // round-to-nearest-even
    return (unsigned short)(u >> 16);
}

__device__ __forceinline__ void gl2lds16(const void* g, void* l) {
    __builtin_amdgcn_global_load_lds(
        (const __attribute__((address_space(1))) unsigned int*)g,
        (__attribute__((address_space(3))) unsigned int*)l, 16, 0, 0);
}

// ---------------- MFMA bf16 GEMM ----------------
// C[M x N](f32, stride ldc) = A[MPAD x K](bf16) @ Bt[N x K](bf16)^T + bias[N]
// 128x128 tile, BK=32, 4 waves (2x2 of 64x64), global_load_lds staging,
// XOR swizzle: LDS slot (row,kc') with kc' = kc ^ ((row>>1)&3)  [2-way max]
__global__ __launch_bounds__(256) void gemm_mfma(
    const unsigned short* __restrict__ A,
    const unsigned short* __restrict__ Bt,
    const float* __restrict__ bias,
    float* __restrict__ C, int M, int N, int K, int ldc)
{
    __shared__ __align__(16) unsigned short As[128 * 32];
    __shared__ __align__(16) unsigned short Bs[128 * 32];
    const int tid  = threadIdx.x;
    const int lane = tid & 63;
    const int wave = tid >> 6;
    const int brow = blockIdx.y * 128;
    const int bcol = blockIdx.x * 128;

    f32x4 acc[4][4] = {};

    const int wr = (wave >> 1) * 64;
    const int wc = (wave & 1) * 64;
    const int swz = (lane >> 4) ^ ((lane >> 1) & 3);   // read-side swizzled k-chunk

    for (int k0 = 0; k0 < K; k0 += 32) {
        #pragma unroll
        for (int i = 0; i < 2; ++i) {
            int s   = i * 256 + wave * 64 + lane;       // LDS 16B-slot index
            int row = s >> 2;
            int kc  = (s & 3) ^ ((s >> 3) & 3);         // inverse swizzle on source
            gl2lds16(A + (size_t)(brow + row) * K + k0 + kc * 8,
                     &As[(i * 256 + wave * 64) * 8]);
            gl2lds16(Bt + (size_t)(bcol + row) * K + k0 + kc * 8,
                     &Bs[(i * 256 + wave * 64) * 8]);
        }
        __syncthreads();

        short8 af[4], bfr[4];
        #pragma unroll
        for (int m = 0; m < 4; ++m) {
            int row = wr + m * 16 + (lane & 15);
            af[m] = *(const short8*)&As[row * 32 + swz * 8];
        }
        #pragma unroll
        for (int n = 0; n < 4; ++n) {
            int col = wc + n * 16 + (lane & 15);
            bfr[n] = *(const short8*)&Bs[col * 32 + swz * 8];
        }
        #pragma unroll
        for (int m = 0; m < 4; ++m)
            #pragma unroll
            for (int n = 0; n < 4; ++n)
                acc[m][n] = __builtin_amdgcn_mfma_f32_16x16x32_bf16(
                    af[m], bfr[n], acc[m][n], 0, 0, 0);
        __syncthreads();
    }

    #pragma unroll
    for (int m = 0; m < 4; ++m) {
        int r0 = brow + wr + m * 16 + (lane >> 4) * 4;
        #pragma unroll
        for (int n = 0; n < 4; ++n) {
            int c = bcol + wc + n * 16 + (lane & 15);
            float bv = bias[c];
            #pragma unroll
            for (int j = 0; j < 4; ++j) {
                int r = r0 + j;
                if (r < M) C[(size_t)r * ldc + c] = acc[m][n][j] + bv;
            }
        }
    }
}

// ---------------- f32 tiled GEMM (kept for small relation tables) ----------------
__global__ __launch_bounds__(256) void gemm_f32(
    const float* __restrict__ A, const float* __restrict__ B,
    float* __restrict__ C, int M, int Nc, int K, int ldc)
{
    __shared__ float As[64][17];
    __shared__ float Bs[16][65];
    int tid = threadIdx.x;
    int tx = tid & 15, ty = tid >> 4;
    int rowBase = blockIdx.y * 64;
    int colBase = blockIdx.x * 64;
    float acc[4][4] = {};
    for (int k0 = 0; k0 < K; k0 += 16) {
        #pragma unroll
        for (int i = 0; i < 4; ++i) {
            int idx = tid + i * 256;
            int r = idx >> 4, k = idx & 15;
            int gr = rowBase + r;
            As[r][k] = (gr < M) ? A[(size_t)gr * K + k0 + k] : 0.f;
        }
        #pragma unroll
        for (int i = 0; i < 4; ++i) {
            int idx = tid + i * 256;
            int k = idx >> 6, c = idx & 63;
            Bs[k][c] = B[(size_t)(k0 + k) * Nc + colBase + c];
        }
        __syncthreads();
        #pragma unroll
        for (int kk = 0; kk < 16; ++kk) {
            float a[4], b[4];
            #pragma unroll
            for (int i = 0; i < 4; ++i) a[i] = As[ty * 4 + i][kk];
            #pragma unroll
            for (int j = 0; j < 4; ++j) b[j] = Bs[kk][tx * 4 + j];
            #pragma unroll
            for (int i = 0; i < 4; ++i)
                #pragma unroll
                for (int j = 0; j < 4; ++j)
                    acc[i][j] += a[i] * b[j];
        }
        __syncthreads();
    }
    #pragma unroll
    for (int i = 0; i < 4; ++i) {
        int gr = rowBase + ty * 4 + i;
        if (gr >= M) continue;
        #pragma unroll
        for (int j = 0; j < 4; ++j) {
            int gc = colBase + tx * 4 + j;
            C[(size_t)gr * ldc + gc] = acc[i][j];
        }
    }
}

// ---------------- conversion / packing helpers ----------------
__global__ void convert_bf16x4(const float* __restrict__ src,
                               unsigned short* __restrict__ dst, int n4)
{
    int i = blockIdx.x * 256 + threadIdx.x;
    if (i >= n4) return;
    float4 v = *(const float4*)&src[(size_t)i * 4];
    ushort4 o;
    o.x = f2bf(v.x); o.y = f2bf(v.y); o.z = f2bf(v.z); o.w = f2bf(v.w);
    *(ushort4*)&dst[(size_t)i * 4] = o;
}

__global__ void transpose_convert(const float* __restrict__ W,
                                  unsigned short* __restrict__ Bt,
                                  int K, int N, int rowoff)
{
    int idx = blockIdx.x * 256 + threadIdx.x;
    if (idx >= K * N) return;
    int n = idx % N, k = idx / N;
    Bt[(size_t)(n + rowoff) * K + k] = f2bf(W[idx]);
}

__global__ void pack2(const float* __restrict__ a, const float* __restrict__ b,
                      float* __restrict__ o, int n)
{
    int i = blockIdx.x * 256 + threadIdx.x;
    if (i < n) { o[i] = a[i]; o[n + i] = b[i]; }
}

__global__ void zero_shorts(unsigned short* __restrict__ p, int n)
{
    int i = blockIdx.x * 256 + threadIdx.x;
    if (i < n) p[i] = 0;
}

// ---------------- CSR build ----------------
__global__ void zero_ints(int* __restrict__ p, int n)
{
    int i = blockIdx.x * blockDim.x + threadIdx.x;
    if (i < n) p[i] = 0;
}

__global__ void count_deg(const int* __restrict__ dst, int* __restrict__ deg, int E)
{
    int i = blockIdx.x * blockDim.x + threadIdx.x;
    if (i < E) atomicAdd(&deg[dst[i]], 1);
}

__global__ __launch_bounds__(256) void scan_block_sums(
    const int* __restrict__ deg, int* __restrict__ bsum, int n)
{
    __shared__ int s[256];
    int i = blockIdx.x * 256 + threadIdx.x;
    s[threadIdx.x] = (i < n) ? deg[i] : 0;
    __syncthreads();
    for (int o = 128; o > 0; o >>= 1) {
        if (threadIdx.x < o) s[threadIdx.x] += s[threadIdx.x + o];
        __syncthreads();
    }
    if (threadIdx.x == 0) bsum[blockIdx.x] = s[0];
}

__global__ __launch_bounds__(256) void scan_bsums(
    const int* __restrict__ bsum, int* __restrict__ boff, int nb)
{
    __shared__ int s[256];
    int v = (threadIdx.x < nb) ? bsum[threadIdx.x] : 0;
    s[threadIdx.x] = v;
    __syncthreads();
    for (int o = 1; o < 256; o <<= 1) {
        int t = (threadIdx.x >= o) ? s[threadIdx.x - o] : 0;
        __syncthreads();
        s[threadIdx.x] += t;
        __syncthreads();
    }
    if (threadIdx.x < nb) boff[threadIdx.x] = s[threadIdx.x] - v; // exclusive
}

__global__ __launch_bounds__(256) void scan_final(
    const int* __restrict__ deg, const int* __restrict__ boff,
    int* __restrict__ offsets, int n)
{
    __shared__ int s[256];
    int i = blockIdx.x * 256 + threadIdx.x;
    int v = (i < n) ? deg[i] : 0;
    s[threadIdx.x] = v;
    __syncthreads();
    for (int o = 1; o < 256; o <<= 1) {
        int t = (threadIdx.x >= o) ? s[threadIdx.x - o] : 0;
        __syncthreads();
        s[threadIdx.x] += t;
        __syncthreads();
    }
    int incl = s[threadIdx.x];
    int excl = incl - v;
    if (i < n) offsets[i] = boff[blockIdx.x] + excl;
    if (i == n - 1) offsets[n] = boff[blockIdx.x] + incl;
}

__global__ void fill_adj(const int* __restrict__ src, const int* __restrict__ rel,
                         const int* __restrict__ dst, const int* __restrict__ offsets,
                         int* __restrict__ cursor,
                         int* __restrict__ adj_src, int* __restrict__ adj_rel, int E)
{
    int e = blockIdx.x * blockDim.x + threadIdx.x;
    if (e < E) {
        int d = dst[e];
        int p = atomicAdd(&cursor[d], 1);
        int slot = offsets[d] + p;
        adj_src[slot] = src[e];
        adj_rel[slot] = rel[e];
    }
}

// ---------------- fused per-node GATv2 attention ----------------
__device__ __forceinline__ float lrelu(float x) { return x > 0.f ? x : NEG_SLOPE * x; }

template <int CPH, bool CONCAT, bool BF16OUT>
__global__ __launch_bounds__(256) void gat_node(
    const float* __restrict__ xlr,      // [n][2*HC]: [xl | xr]
    const float* __restrict__ erel,     // [NR][HC] relations@We
    const int* __restrict__ adj_src, const int* __restrict__ adj_rel,
    const int* __restrict__ offsets,
    const float* __restrict__ att,      // [HC]
    const float* __restrict__ bias,     // CONCAT ? [HC] : [CPH]
    void* __restrict__ out, int n)
{
    constexpr int HC  = NH * CPH;
    constexpr int VPL = HC / 64;
    int lane = threadIdx.x & 63;
    int wave = threadIdx.x >> 6;
    int v = blockIdx.x * 4 + wave;
    if (v >= n) return;

    const float* xlrow = xlr + (size_t)v * (2 * HC) + lane * VPL;
    const float* xrrow = xlrow + HC;
    float xr_v[VPL], xl_v[VPL], attv[VPL], acc[VPL];
    #pragma unroll
    for (int j = 0; j < VPL; j += 4) {
        *(float4*)&xl_v[j] = *(const float4*)&xlrow[j];
        *(float4*)&xr_v[j] = *(const float4*)&xrrow[j];
        *(float4*)&attv[j] = *(const float4*)&att[lane * VPL + j];
    }

    // self loop
    float part = 0.f;
    #pragma unroll
    for (int j = 0; j < VPL; ++j) part += lrelu(xl_v[j] + xr_v[j]) * attv[j];
    part += __shfl_xor(part, 1);
    part += __shfl_xor(part, 2);
    part += __shfl_xor(part, 4);
    part += __shfl_xor(part, 8);
    float m_run = part, l_run = 1.f;
    #pragma unroll
    for (int j = 0; j < VPL; ++j) acc[j] = xl_v[j];

    int beg = offsets[v], end = offsets[v + 1];
    for (int idx = beg; idx < end; ++idx) {
        int s = adj_src[idx], r = adj_rel[idx];
        const float* xls = xlr + (size_t)s * (2 * HC) + lane * VPL;
        const float* er  = erel + (size_t)r * HC + lane * VPL;
        float xv[VPL], ev[VPL];
        #pragma unroll
        for (int j = 0; j < VPL; j += 4) {
            *(float4*)&xv[j] = *(const float4*)&xls[j];
            *(float4*)&ev[j] = *(const float4*)&er[j];
        }
        float p2 = 0.f;
        #pragma unroll
        for (int j = 0; j < VPL; ++j) p2 += lrelu(xv[j] + xr_v[j] + ev[j]) * attv[j];
        p2 += __shfl_xor(p2, 1);
        p2 += __shfl_xor(p2, 2);
        p2 += __shfl_xor(p2, 4);
        p2 += __shfl_xor(p2, 8);
        float mn = fmaxf(m_run, p2);
        float sc = expf(m_run - mn);
        float p  = expf(p2 - mn);
        l_run = l_run * sc + p;
        #pragma unroll
        for (int j = 0; j < VPL; ++j) acc[j] = acc[j] * sc + p * xv[j];
        m_run = mn;
    }

    float inv = 1.f / l_run;
    if (CONCAT) {
        if (BF16OUT) {
            unsigned short* ob = (unsigned short*)out;
            ushort4 pk;
            float r0 = acc[0] * inv + bias[lane * VPL + 0];
            float r1 = acc[1] * inv + bias[lane * VPL + 1];
            float r2 = acc[2] * inv + bias[lane * VPL + 2];
            float r3 = acc[3] * inv + bias[lane * VPL + 3];
            pk.x = f2bf(r0); pk.y = f2bf(r1); pk.z = f2bf(r2); pk.w = f2bf(r3);
            *(ushort4*)&ob[(size_t)v * HC + lane * VPL] = pk;
        } else {
            float* of = (float*)out;
            #pragma unroll
            for (int j = 0; j < VPL; ++j)
                of[(size_t)v * HC + lane * VPL + j] = acc[j] * inv + bias[lane * VPL + j];
        }
    } else {
        float* of = (float*)out;
        float t[VPL];
        #pragma unroll
        for (int j = 0; j < VPL; ++j) {
            t[j] = acc[j] * inv;
            t[j] += __shfl_xor(t[j], 16);
            t[j] += __shfl_xor(t[j], 32);
        }
        if (lane < 16) {
            #pragma unroll
            for (int j = 0; j < VPL; ++j)
                of[(size_t)v * CPH + lane * VPL + j] = 0.25f * t[j] + bias[lane * VPL + j];
        }
    }
}

// ---------------- host launcher ----------------
extern "C" void kernel_launch(void* const* d_in, const int* in_sizes, int n_in,
                              void* d_out, int out_size, void* d_ws, size_t ws_size,
                              hipStream_t stream)
{
    const float* x         = (const float*)d_in[0];
    const int*   ei        = (const int*)d_in[1];
    const float* relations = (const float*)d_in[2];
    const float* Wl1  = (const float*)d_in[3];
    const float* bl1  = (const float*)d_in[4];
    const float* Wr1  = (const float*)d_in[5];
    const float* br1  = (const float*)d_in[6];
    const float* We1  = (const float*)d_in[7];
    const float* att1 = (const float*)d_in[8];
    const float* bias1= (const float*)d_in[9];
    const float* Wl2  = (const float*)d_in[10];
    const float* bl2  = (const float*)d_in[11];
    const float* Wr2  = (const float*)d_in[12];
    const float* br2  = (const float*)d_in[13];
    const float* We2  = (const float*)d_in[14];
    const float* att2 = (const float*)d_in[15];
    const float* bias2= (const float*)d_in[16];
    float* out = (float*)d_out;

    const int* src = ei;
    const int* rel = ei + NE;
    const int* dst = ei + 2 * NE;

    // ---- workspace layout ----
    float* xlrBig = (float*)d_ws;                              // NN*1024 f32
    float* erel1  = xlrBig + (size_t)NN * 1024;                // NR*256
    float* erel2  = erel1 + (size_t)NR * 256;                  // NR*512
    float* pb1    = erel2 + (size_t)NR * 512;                  // 512
    float* pb2    = pb1 + 512;                                 // 1024
    unsigned short* xbf = (unsigned short*)(pb2 + 1024);       // MPAD*128 bf16
    unsigned short* hbf = xbf + (size_t)MPAD * 128;            // MPAD*256 bf16
    unsigned short* Bt1 = hbf + (size_t)MPAD * 256;            // 512*128
    unsigned short* Bt2 = Bt1 + 512 * 128;                     // 1024*256
    int* ibuf    = (int*)(Bt2 + 1024 * 256);
    int* deg     = ibuf;
    int* offsets = deg + NN;          // NN+1
    int* cursor  = offsets + NN + 1;
    int* bsum    = cursor + NN;       // 256
    int* boff    = bsum + 256;        // 256
    int* adj_src = boff + 256;        // NE
    int* adj_rel = adj_src + NE;      // NE

    const int NB = (NN + 255) / 256;
    const int EB = (NE + 255) / 256;
    const int MB128 = MPAD / 128;     // 391

    // --- CSR by destination ---
    zero_ints<<<NB, 256, 0, stream>>>(deg, NN);
    zero_ints<<<NB, 256, 0, stream>>>(cursor, NN);
    count_deg<<<EB, 256, 0, stream>>>(dst, deg, NE);
    scan_block_sums<<<NB, 256, 0, stream>>>(deg, bsum, NN);
    scan_bsums<<<1, 256, 0, stream>>>(bsum, boff, NB);
    scan_final<<<NB, 256, 0, stream>>>(deg, boff, offsets, NN);
    fill_adj<<<EB, 256, 0, stream>>>(src, rel, dst, offsets, cursor, adj_src, adj_rel, NE);

    // --- relation edge-embedding tables (f32, tiny) ---
    gemm_f32<<<dim3(4, (NR + 63) / 64), 256, 0, stream>>>(relations, We1, erel1, NR, 256, INF_, 256);
    gemm_f32<<<dim3(8, (NR + 63) / 64), 256, 0, stream>>>(relations, We2, erel2, NR, 512, INF_, 512);

    // --- conversions / weight packing ---
    convert_bf16x4<<<(NN * INF_ / 4 + 255) / 256, 256, 0, stream>>>(x, xbf, NN * INF_ / 4);
    zero_shorts<<<((MPAD - NN) * 128 + 255) / 256, 256, 0, stream>>>(xbf + (size_t)NN * 128, (MPAD - NN) * 128);
    zero_shorts<<<((MPAD - NN) * 256 + 255) / 256, 256, 0, stream>>>(hbf + (size_t)NN * 256, (MPAD - NN) * 256);
    transpose_convert<<<(128 * 256 + 255) / 256, 256, 0, stream>>>(Wl1, Bt1, 128, 256, 0);
    transpose_convert<<<(128 * 256 + 255) / 256, 256, 0, stream>>>(Wr1, Bt1, 128, 256, 256);
    transpose_convert<<<(256 * 512 + 255) / 256, 256, 0, stream>>>(Wl2, Bt2, 256, 512, 0);
    transpose_convert<<<(256 * 512 + 255) / 256, 256, 0, stream>>>(Wr2, Bt2, 256, 512, 512);
    pack2<<<1, 256, 0, stream>>>(bl1, br1, pb1, 256);
    pack2<<<2, 256, 0, stream>>>(bl2, br2, pb2, 512);

    // --- layer 1 transform: xlr1 = [x@Wl1+bl1 | x@Wr1+br1]  (one fused MFMA GEMM) ---
    gemm_mfma<<<dim3(4, MB128), 256, 0, stream>>>(xbf, Bt1, pb1, xlrBig, NN, 512, 128, 512);

    // --- layer 1 attention -> h (bf16) ---
    gat_node<HIDC, true, true><<<(NN + 3) / 4, 256, 0, stream>>>(
        xlrBig, erel1, adj_src, adj_rel, offsets, att1, bias1, hbf, NN);

    // --- layer 2 transform: xlr2 = [h@Wl2+bl2 | h@Wr2+br2] ---
    gemm_mfma<<<dim3(8, MB128), 256, 0, stream>>>(hbf, Bt2, pb2, xlrBig, NN, 1024, 256, 1024);

    // --- layer 2 attention (mean over heads) -> out ---
    gat_node<OUTC, false, false><<<(NN + 3) / 4, 256, 0, stream>>>(
        xlrBig, erel2, adj_src, adj_rel, offsets, att2, bias2, out, NN);
}

// Round 3
// 382.339 us; speedup vs baseline: 2.7199x; 1.2372x over previous
//
#include <hip/hip_runtime.h>
#include <math.h>

#define NEG_SLOPE 0.2f

constexpr int NN   = 50000;   // nodes
constexpr int NE   = 400000;  // edges
constexpr int NR   = 500;     // relations
constexpr int INF_ = 128;     // input feat
constexpr int HIDC = 64;      // layer1 per-head channels
constexpr int NH   = 4;       // heads
constexpr int OUTC = 128;     // layer2 per-head channels
constexpr int MPAD = 50048;   // 391 * 128

typedef __attribute__((ext_vector_type(8))) short short8;
typedef __attribute__((ext_vector_type(4))) float f32x4;

__device__ __forceinline__ unsigned short f2bf(float f) {
    unsigned u = __float_as_uint(f);
    u += 0x7FFF + ((u >> 16) & 1);   // round-to-nearest-even
    return (unsigned short)(u >> 16);
}
__device__ __forceinline__ float bf2f(unsigned short u) {
    return __uint_as_float(((unsigned)u) << 16);
}

__device__ __forceinline__ void gl2lds16(const void* g, void* l) {
    __builtin_amdgcn_global_load_lds(
        (const __attribute__((address_space(1))) unsigned int*)g,
        (__attribute__((address_space(3))) unsigned int*)l, 16, 0, 0);
}

// ---------------- MFMA bf16 GEMM ----------------
// C[M x N](stride ldc) = A[MPAD x K](bf16) @ Bt[N x K](bf16)^T + bias[N]
// 128x128 tile, BK=32, 4 waves (2x2 of 64x64), global_load_lds staging,
// XOR swizzle: LDS slot (row,kc') with kc' = kc ^ ((row>>1)&3)  [2-way max]
template <bool BF16C>
__global__ __launch_bounds__(256) void gemm_mfma(
    const unsigned short* __restrict__ A,
    const unsigned short* __restrict__ Bt,
    const float* __restrict__ bias,
    void* __restrict__ Cv, int M, int N, int K, int ldc)
{
    __shared__ __align__(16) unsigned short As[128 * 32];
    __shared__ __align__(16) unsigned short Bs[128 * 32];
    const int tid  = threadIdx.x;
    const int lane = tid & 63;
    const int wave = tid >> 6;
    const int brow = blockIdx.y * 128;
    const int bcol = blockIdx.x * 128;

    f32x4 acc[4][4] = {};

    const int wr = (wave >> 1) * 64;
    const int wc = (wave & 1) * 64;
    const int swz = (lane >> 4) ^ ((lane >> 1) & 3);   // read-side swizzled k-chunk

    for (int k0 = 0; k0 < K; k0 += 32) {
        #pragma unroll
        for (int i = 0; i < 2; ++i) {
            int s   = i * 256 + wave * 64 + lane;       // LDS 16B-slot index
            int row = s >> 2;
            int kc  = (s & 3) ^ ((s >> 3) & 3);         // inverse swizzle on source
            gl2lds16(A + (size_t)(brow + row) * K + k0 + kc * 8,
                     &As[(i * 256 + wave * 64) * 8]);
            gl2lds16(Bt + (size_t)(bcol + row) * K + k0 + kc * 8,
                     &Bs[(i * 256 + wave * 64) * 8]);
        }
        __syncthreads();

        short8 af[4], bfr[4];
        #pragma unroll
        for (int m = 0; m < 4; ++m) {
            int row = wr + m * 16 + (lane & 15);
            af[m] = *(const short8*)&As[row * 32 + swz * 8];
        }
        #pragma unroll
        for (int n = 0; n < 4; ++n) {
            int col = wc + n * 16 + (lane & 15);
            bfr[n] = *(const short8*)&Bs[col * 32 + swz * 8];
        }
        #pragma unroll
        for (int m = 0; m < 4; ++m)
            #pragma unroll
            for (int n = 0; n < 4; ++n)
                acc[m][n] = __builtin_amdgcn_mfma_f32_16x16x32_bf16(
                    af[m], bfr[n], acc[m][n], 0, 0, 0);
        __syncthreads();
    }

    #pragma unroll
    for (int m = 0; m < 4; ++m) {
        int r0 = brow + wr + m * 16 + (lane >> 4) * 4;
        #pragma unroll
        for (int n = 0; n < 4; ++n) {
            int c = bcol + wc + n * 16 + (lane & 15);
            float bv = bias[c];
            #pragma unroll
            for (int j = 0; j < 4; ++j) {
                int r = r0 + j;
                if (r < M) {
                    float v = acc[m][n][j] + bv;
                    if constexpr (BF16C)
                        ((unsigned short*)Cv)[(size_t)r * ldc + c] = f2bf(v);
                    else
                        ((float*)Cv)[(size_t)r * ldc + c] = v;
                }
            }
        }
    }
}

// ---------------- f32 tiled GEMM (small relation tables) ----------------
__global__ __launch_bounds__(256) void gemm_f32(
    const float* __restrict__ A, const float* __restrict__ B,
    float* __restrict__ C, int M, int Nc, int K, int ldc)
{
    __shared__ float As[64][17];
    __shared__ float Bs[16][65];
    int tid = threadIdx.x;
    int tx = tid & 15, ty = tid >> 4;
    int rowBase = blockIdx.y * 64;
    int colBase = blockIdx.x * 64;
    float acc[4][4] = {};
    for (int k0 = 0; k0 < K; k0 += 16) {
        #pragma unroll
        for (int i = 0; i < 4; ++i) {
            int idx = tid + i * 256;
            int r = idx >> 4, k = idx & 15;
            int gr = rowBase + r;
            As[r][k] = (gr < M) ? A[(size_t)gr * K + k0 + k] : 0.f;
        }
        #pragma unroll
        for (int i = 0; i < 4; ++i) {
            int idx = tid + i * 256;
            int k = idx >> 6, c = idx & 63;
            Bs[k][c] = B[(size_t)(k0 + k) * Nc + colBase + c];
        }
        __syncthreads();
        #pragma unroll
        for (int kk = 0; kk < 16; ++kk) {
            float a[4], b[4];
            #pragma unroll
            for (int i = 0; i < 4; ++i) a[i] = As[ty * 4 + i][kk];
            #pragma unroll
            for (int j = 0; j < 4; ++j) b[j] = Bs[kk][tx * 4 + j];
            #pragma unroll
            for (int i = 0; i < 4; ++i)
                #pragma unroll
                for (int j = 0; j < 4; ++j)
                    acc[i][j] += a[i] * b[j];
        }
        __syncthreads();
    }
    #pragma unroll
    for (int i = 0; i < 4; ++i) {
        int gr = rowBase + ty * 4 + i;
        if (gr >= M) continue;
        #pragma unroll
        for (int j = 0; j < 4; ++j) {
            int gc = colBase + tx * 4 + j;
            C[(size_t)gr * ldc + gc] = acc[i][j];
        }
    }
}

// ---------------- conversion / packing helpers ----------------
__global__ void convert_bf16x4(const float* __restrict__ src,
                               unsigned short* __restrict__ dst, int n4)
{
    int i = blockIdx.x * 256 + threadIdx.x;
    if (i >= n4) return;
    float4 v = *(const float4*)&src[(size_t)i * 4];
    ushort4 o;
    o.x = f2bf(v.x); o.y = f2bf(v.y); o.z = f2bf(v.z); o.w = f2bf(v.w);
    *(ushort4*)&dst[(size_t)i * 4] = o;
}

__global__ void transpose_convert(const float* __restrict__ W,
                                  unsigned short* __restrict__ Bt,
                                  int K, int N, int rowoff)
{
    int idx = blockIdx.x * 256 + threadIdx.x;
    if (idx >= K * N) return;
    int n = idx % N, k = idx / N;
    Bt[(size_t)(n + rowoff) * K + k] = f2bf(W[idx]);
}

__global__ void pack2(const float* __restrict__ a, const float* __restrict__ b,
                      float* __restrict__ o, int n)
{
    int i = blockIdx.x * 256 + threadIdx.x;
    if (i < n) { o[i] = a[i]; o[n + i] = b[i]; }
}

__global__ void zero_shorts(unsigned short* __restrict__ p, int n)
{
    int i = blockIdx.x * 256 + threadIdx.x;
    if (i < n) p[i] = 0;
}

// ---------------- CSR build ----------------
__global__ void zero_ints(int* __restrict__ p, int n)
{
    int i = blockIdx.x * blockDim.x + threadIdx.x;
    if (i < n) p[i] = 0;
}

__global__ void count_deg(const int* __restrict__ dst, int* __restrict__ deg, int E)
{
    int i = blockIdx.x * blockDim.x + threadIdx.x;
    if (i < E) atomicAdd(&deg[dst[i]], 1);
}

__global__ __launch_bounds__(256) void scan_block_sums(
    const int* __restrict__ deg, int* __restrict__ bsum, int n)
{
    __shared__ int s[256];
    int i = blockIdx.x * 256 + threadIdx.x;
    s[threadIdx.x] = (i < n) ? deg[i] : 0;
    __syncthreads();
    for (int o = 128; o > 0; o >>= 1) {
        if (threadIdx.x < o) s[threadIdx.x] += s[threadIdx.x + o];
        __syncthreads();
    }
    if (threadIdx.x == 0) bsum[blockIdx.x] = s[0];
}

__global__ __launch_bounds__(256) void scan_bsums(
    const int* __restrict__ bsum, int* __restrict__ boff, int nb)
{
    __shared__ int s[256];
    int v = (threadIdx.x < nb) ? bsum[threadIdx.x] : 0;
    s[threadIdx.x] = v;
    __syncthreads();
    for (int o = 1; o < 256; o <<= 1) {
        int t = (threadIdx.x >= o) ? s[threadIdx.x - o] : 0;
        __syncthreads();
        s[threadIdx.x] += t;
        __syncthreads();
    }
    if (threadIdx.x < nb) boff[threadIdx.x] = s[threadIdx.x] - v; // exclusive
}

__global__ __launch_bounds__(256) void scan_final(
    const int* __restrict__ deg, const int* __restrict__ boff,
    int* __restrict__ offsets, int n)
{
    __shared__ int s[256];
    int i = blockIdx.x * 256 + threadIdx.x;
    int v = (i < n) ? deg[i] : 0;
    s[threadIdx.x] = v;
    __syncthreads();
    for (int o = 1; o < 256; o <<= 1) {
        int t = (threadIdx.x >= o) ? s[threadIdx.x - o] : 0;
        __syncthreads();
        s[threadIdx.x] += t;
        __syncthreads();
    }
    int incl = s[threadIdx.x];
    int excl = incl - v;
    if (i < n) offsets[i] = boff[blockIdx.x] + excl;
    if (i == n - 1) offsets[n] = boff[blockIdx.x] + incl;
}

__global__ void fill_adj(const int* __restrict__ src, const int* __restrict__ rel,
                         const int* __restrict__ dst, const int* __restrict__ offsets,
                         int* __restrict__ cursor,
                         int* __restrict__ adj_src, int* __restrict__ adj_rel, int E)
{
    int e = blockIdx.x * blockDim.x + threadIdx.x;
    if (e < E) {
        int d = dst[e];
        int p = atomicAdd(&cursor[d], 1);
        int slot = offsets[d] + p;
        adj_src[slot] = src[e];
        adj_rel[slot] = rel[e];
    }
}

// ---------------- fused per-node GATv2 attention (bf16 inputs) ----------------
__device__ __forceinline__ float lrelu(float x) { return x > 0.f ? x : NEG_SLOPE * x; }

template <int CPH, bool CONCAT, bool BF16OUT>
__global__ __launch_bounds__(256) void gat_node(
    const unsigned short* __restrict__ xlr,   // [n][2*HC] bf16: [xl | xr]
    const unsigned short* __restrict__ erel,  // [NR][HC] bf16 relations@We
    const int* __restrict__ adj_src, const int* __restrict__ adj_rel,
    const int* __restrict__ offsets,
    const float* __restrict__ att,            // [HC]
    const float* __restrict__ bias,           // CONCAT ? [HC] : [CPH]
    void* __restrict__ out, int n)
{
    constexpr int HC  = NH * CPH;
    constexpr int VPL = HC / 64;
    int lane = threadIdx.x & 63;
    int wave = threadIdx.x >> 6;
    int v = blockIdx.x * 4 + wave;
    if (v >= n) return;

    const unsigned short* xlrow = xlr + (size_t)v * (2 * HC) + lane * VPL;
    const unsigned short* xrrow = xlrow + HC;

    unsigned short xlraw[VPL], xrraw[VPL];
    float xr_v[VPL], xl_v[VPL], attv[VPL], acc[VPL];
    #pragma unroll
    for (int j = 0; j < VPL; j += 4) {
        *(ushort4*)&xlraw[j] = *(const ushort4*)&xlrow[j];
        *(ushort4*)&xrraw[j] = *(const ushort4*)&xrrow[j];
        *(float4*)&attv[j]   = *(const float4*)&att[lane * VPL + j];
    }
    #pragma unroll
    for (int j = 0; j < VPL; ++j) { xl_v[j] = bf2f(xlraw[j]); xr_v[j] = bf2f(xrraw[j]); }

    // self loop
    float part = 0.f;
    #pragma unroll
    for (int j = 0; j < VPL; ++j) part += lrelu(xl_v[j] + xr_v[j]) * attv[j];
    part += __shfl_xor(part, 1);
    part += __shfl_xor(part, 2);
    part += __shfl_xor(part, 4);
    part += __shfl_xor(part, 8);
    float m_run = part, l_run = 1.f;
    #pragma unroll
    for (int j = 0; j < VPL; ++j) acc[j] = xl_v[j];

    int beg = offsets[v], end = offsets[v + 1];
    int idx = beg;
    for (; idx + 2 <= end; idx += 2) {
        int s0 = adj_src[idx],     r0 = adj_rel[idx];
        int s1 = adj_src[idx + 1], r1 = adj_rel[idx + 1];
        const unsigned short* x0 = xlr + (size_t)s0 * (2 * HC) + lane * VPL;
        const unsigned short* e0 = erel + (size_t)r0 * HC + lane * VPL;
        const unsigned short* x1 = xlr + (size_t)s1 * (2 * HC) + lane * VPL;
        const unsigned short* e1 = erel + (size_t)r1 * HC + lane * VPL;
        unsigned short xr0[VPL], er0[VPL], xr1[VPL], er1[VPL];
        #pragma unroll
        for (int j = 0; j < VPL; j += 4) {
            *(ushort4*)&xr0[j] = *(const ushort4*)&x0[j];
            *(ushort4*)&er0[j] = *(const ushort4*)&e0[j];
            *(ushort4*)&xr1[j] = *(const ushort4*)&x1[j];
            *(ushort4*)&er1[j] = *(const ushort4*)&e1[j];
        }
        float xv0[VPL], xv1[VPL];
        float p0 = 0.f, p1 = 0.f;
        #pragma unroll
        for (int j = 0; j < VPL; ++j) {
            xv0[j] = bf2f(xr0[j]);
            xv1[j] = bf2f(xr1[j]);
            p0 += lrelu(xv0[j] + xr_v[j] + bf2f(er0[j])) * attv[j];
            p1 += lrelu(xv1[j] + xr_v[j] + bf2f(er1[j])) * attv[j];
        }
        p0 += __shfl_xor(p0, 1); p1 += __shfl_xor(p1, 1);
        p0 += __shfl_xor(p0, 2); p1 += __shfl_xor(p1, 2);
        p0 += __shfl_xor(p0, 4); p1 += __shfl_xor(p1, 4);
        p0 += __shfl_xor(p0, 8); p1 += __shfl_xor(p1, 8);
        float mn = fmaxf(fmaxf(m_run, p0), p1);   // v_max3
        float sc = expf(m_run - mn);
        float w0 = expf(p0 - mn);
        float w1 = expf(p1 - mn);
        l_run = l_run * sc + w0 + w1;
        #pragma unroll
        for (int j = 0; j < VPL; ++j)
            acc[j] = acc[j] * sc + w0 * xv0[j] + w1 * xv1[j];
        m_run = mn;
    }
    if (idx < end) {
        int s0 = adj_src[idx], r0 = adj_rel[idx];
        const unsigned short* x0 = xlr + (size_t)s0 * (2 * HC) + lane * VPL;
        const unsigned short* e0 = erel + (size_t)r0 * HC + lane * VPL;
        unsigned short xr0[VPL], er0[VPL];
        #pragma unroll
        for (int j = 0; j < VPL; j += 4) {
            *(ushort4*)&xr0[j] = *(const ushort4*)&x0[j];
            *(ushort4*)&er0[j] = *(const ushort4*)&e0[j];
        }
        float xv0[VPL];
        float p0 = 0.f;
        #pragma unroll
        for (int j = 0; j < VPL; ++j) {
            xv0[j] = bf2f(xr0[j]);
            p0 += lrelu(xv0[j] + xr_v[j] + bf2f(er0[j])) * attv[j];
        }
        p0 += __shfl_xor(p0, 1);
        p0 += __shfl_xor(p0, 2);
        p0 += __shfl_xor(p0, 4);
        p0 += __shfl_xor(p0, 8);
        float mn = fmaxf(m_run, p0);
        float sc = expf(m_run - mn);
        float w0 = expf(p0 - mn);
        l_run = l_run * sc + w0;
        #pragma unroll
        for (int j = 0; j < VPL; ++j) acc[j] = acc[j] * sc + w0 * xv0[j];
        m_run = mn;
    }

    float inv = 1.f / l_run;
    if (CONCAT) {
        if (BF16OUT) {
            unsigned short* ob = (unsigned short*)out;
            unsigned short pk[VPL];
            #pragma unroll
            for (int j = 0; j < VPL; ++j)
                pk[j] = f2bf(acc[j] * inv + bias[lane * VPL + j]);
            #pragma unroll
            for (int j = 0; j < VPL; j += 4)
                *(ushort4*)&ob[(size_t)v * HC + lane * VPL + j] = *(ushort4*)&pk[j];
        } else {
            float* of = (float*)out;
            #pragma unroll
            for (int j = 0; j < VPL; ++j)
                of[(size_t)v * HC + lane * VPL + j] = acc[j] * inv + bias[lane * VPL + j];
        }
    } else {
        float* of = (float*)out;
        float t[VPL];
        #pragma unroll
        for (int j = 0; j < VPL; ++j) {
            t[j] = acc[j] * inv;
            t[j] += __shfl_xor(t[j], 16);
            t[j] += __shfl_xor(t[j], 32);
        }
        if (lane < 16) {
            #pragma unroll
            for (int j = 0; j < VPL; ++j)
                of[(size_t)v * CPH + lane * VPL + j] = 0.25f * t[j] + bias[lane * VPL + j];
        }
    }
}

// ---------------- host launcher ----------------
extern "C" void kernel_launch(void* const* d_in, const int* in_sizes, int n_in,
                              void* d_out, int out_size, void* d_ws, size_t ws_size,
                              hipStream_t stream)
{
    const float* x         = (const float*)d_in[0];
    const int*   ei        = (const int*)d_in[1];
    const float* relations = (const float*)d_in[2];
    const float* Wl1  = (const float*)d_in[3];
    const float* bl1  = (const float*)d_in[4];
    const float* Wr1  = (const float*)d_in[5];
    const float* br1  = (const float*)d_in[6];
    const float* We1  = (const float*)d_in[7];
    const float* att1 = (const float*)d_in[8];
    const float* bias1= (const float*)d_in[9];
    const float* Wl2  = (const float*)d_in[10];
    const float* bl2  = (const float*)d_in[11];
    const float* Wr2  = (const float*)d_in[12];
    const float* br2  = (const float*)d_in[13];
    const float* We2  = (const float*)d_in[14];
    const float* att2 = (const float*)d_in[15];
    const float* bias2= (const float*)d_in[16];
    float* out = (float*)d_out;

    const int* src = ei;
    const int* rel = ei + NE;
    const int* dst = ei + 2 * NE;

    // ---- workspace layout ----
    float* erel1f = (float*)d_ws;                              // NR*256 f32
    float* erel2f = erel1f + (size_t)NR * 256;                 // NR*512 f32
    float* pb1    = erel2f + (size_t)NR * 512;                 // 512
    float* pb2    = pb1 + 512;                                 // 1024
    unsigned short* xlrbf  = (unsigned short*)(pb2 + 1024);    // NN*1024 bf16
    unsigned short* xbf    = xlrbf + (size_t)NN * 1024;        // MPAD*128
    unsigned short* hbf    = xbf + (size_t)MPAD * 128;         // MPAD*256
    unsigned short* Bt1    = hbf + (size_t)MPAD * 256;         // 512*128
    unsigned short* Bt2    = Bt1 + 512 * 128;                  // 1024*256
    unsigned short* erel1b = Bt2 + 1024 * 256;                 // NR*256
    unsigned short* erel2b = erel1b + NR * 256;                // NR*512
    int* ibuf    = (int*)(erel2b + NR * 512);
    int* deg     = ibuf;
    int* offsets = deg + NN;          // NN+1
    int* cursor  = offsets + NN + 1;
    int* bsum    = cursor + NN;       // 256
    int* boff    = bsum + 256;        // 256
    int* adj_src = boff + 256;        // NE
    int* adj_rel = adj_src + NE;      // NE

    const int NB = (NN + 255) / 256;
    const int EB = (NE + 255) / 256;
    const int MB128 = MPAD / 128;     // 391

    // --- CSR by destination ---
    zero_ints<<<NB, 256, 0, stream>>>(deg, NN);
    zero_ints<<<NB, 256, 0, stream>>>(cursor, NN);
    count_deg<<<EB, 256, 0, stream>>>(dst, deg, NE);
    scan_block_sums<<<NB, 256, 0, stream>>>(deg, bsum, NN);
    scan_bsums<<<1, 256, 0, stream>>>(bsum, boff, NB);
    scan_final<<<NB, 256, 0, stream>>>(deg, boff, offsets, NN);
    fill_adj<<<EB, 256, 0, stream>>>(src, rel, dst, offsets, cursor, adj_src, adj_rel, NE);

    // --- relation edge-embedding tables (f32 -> bf16) ---
    gemm_f32<<<dim3(4, (NR + 63) / 64), 256, 0, stream>>>(relations, We1, erel1f, NR, 256, INF_, 256);
    gemm_f32<<<dim3(8, (NR + 63) / 64), 256, 0, stream>>>(relations, We2, erel2f, NR, 512, INF_, 512);
    convert_bf16x4<<<(NR * 256 / 4 + 255) / 256, 256, 0, stream>>>(erel1f, erel1b, NR * 256 / 4);
    convert_bf16x4<<<(NR * 512 / 4 + 255) / 256, 256, 0, stream>>>(erel2f, erel2b, NR * 512 / 4);

    // --- conversions / weight packing ---
    convert_bf16x4<<<(NN * INF_ / 4 + 255) / 256, 256, 0, stream>>>(x, xbf, NN * INF_ / 4);
    zero_shorts<<<((MPAD - NN) * 128 + 255) / 256, 256, 0, stream>>>(xbf + (size_t)NN * 128, (MPAD - NN) * 128);
    zero_shorts<<<((MPAD - NN) * 256 + 255) / 256, 256, 0, stream>>>(hbf + (size_t)NN * 256, (MPAD - NN) * 256);
    transpose_convert<<<(128 * 256 + 255) / 256, 256, 0, stream>>>(Wl1, Bt1, 128, 256, 0);
    transpose_convert<<<(128 * 256 + 255) / 256, 256, 0, stream>>>(Wr1, Bt1, 128, 256, 256);
    transpose_convert<<<(256 * 512 + 255) / 256, 256, 0, stream>>>(Wl2, Bt2, 256, 512, 0);
    transpose_convert<<<(256 * 512 + 255) / 256, 256, 0, stream>>>(Wr2, Bt2, 256, 512, 512);
    pack2<<<1, 256, 0, stream>>>(bl1, br1, pb1, 256);
    pack2<<<2, 256, 0, stream>>>(bl2, br2, pb2, 512);

    // --- layer 1 transform: xlr1(bf16) = [x@Wl1+bl1 | x@Wr1+br1] ---
    gemm_mfma<true><<<dim3(4, MB128), 256, 0, stream>>>(xbf, Bt1, pb1, xlrbf, NN, 512, 128, 512);

    // --- layer 1 attention -> h (bf16) ---
    gat_node<HIDC, true, true><<<(NN + 3) / 4, 256, 0, stream>>>(
        xlrbf, erel1b, adj_src, adj_rel, offsets, att1, bias1, hbf, NN);

    // --- layer 2 transform: xlr2(bf16) = [h@Wl2+bl2 | h@Wr2+br2] ---
    gemm_mfma<true><<<dim3(8, MB128), 256, 0, stream>>>(hbf, Bt2, pb2, xlrbf, NN, 1024, 256, 1024);

    // --- layer 2 attention (mean over heads) -> out ---
    gat_node<OUTC, false, false><<<(NN + 3) / 4, 256, 0, stream>>>(
        xlrbf, erel2b, adj_src, adj_rel, offsets, att2, bias2, out, NN);
}

// Round 4
// 327.254 us; speedup vs baseline: 3.1777x; 1.1683x over previous
//
#include <hip/hip_runtime.h>
#include <math.h>

constexpr int NN   = 50000;   // nodes
constexpr int NE   = 400000;  // edges
constexpr int NR   = 500;     // relations
constexpr int INF_ = 128;     // input feat
constexpr int HIDC = 64;      // layer1 per-head channels
constexpr int NH   = 4;       // heads
constexpr int OUTC = 128;     // layer2 per-head channels
constexpr int MPAD = 50048;   // 391 * 128

typedef __attribute__((ext_vector_type(2))) _Float16 h2;
typedef __attribute__((ext_vector_type(4))) _Float16 h4;
typedef __attribute__((ext_vector_type(8))) _Float16 h8;
typedef __attribute__((ext_vector_type(4))) float f32x4;

__device__ __forceinline__ h2 b2(float f) {
    _Float16 h = (_Float16)f;
    return (h2){h, h};
}

__device__ __forceinline__ h2 lrelu2(h2 x) {
    h2 t = x * (h2){(_Float16)0.2f, (_Float16)0.2f};
#if __has_builtin(__builtin_elementwise_max)
    return __builtin_elementwise_max(x, t);
#else
    h2 r;
    r[0] = x[0] > t[0] ? x[0] : t[0];
    r[1] = x[1] > t[1] ? x[1] : t[1];
    return r;
#endif
}

__device__ __forceinline__ float fdot2a(h2 a, h2 b, float c) {
#if __has_builtin(__builtin_amdgcn_fdot2)
    return __builtin_amdgcn_fdot2(a, b, c, false);
#else
    return c + (float)a[0] * (float)b[0] + (float)a[1] * (float)b[1];
#endif
}

template <int NP>
__device__ __forceinline__ void load_h(const _Float16* p, h2* d) {
    if constexpr (NP == 2) {
        h4 t = *(const h4*)p;
        d[0] = (h2){t[0], t[1]}; d[1] = (h2){t[2], t[3]};
    } else {
        h8 t = *(const h8*)p;
        d[0] = (h2){t[0], t[1]}; d[1] = (h2){t[2], t[3]};
        d[2] = (h2){t[4], t[5]}; d[3] = (h2){t[6], t[7]};
    }
}

__device__ __forceinline__ void gl2lds16(const void* g, void* l) {
    __builtin_amdgcn_global_load_lds(
        (const __attribute__((address_space(1))) unsigned int*)g,
        (__attribute__((address_space(3))) unsigned int*)l, 16, 0, 0);
}

// ---------------- MFMA f16 GEMM ----------------
// C[M x N](f16, stride ldc) = A[* x K](f16) @ Bt[N x K](f16)^T + bias[N]
// 128x128 tile, BK=32, 4 waves (2x2 of 64x64), global_load_lds staging,
// XOR swizzle on 16B chunks (<=2-way LDS conflict = free)
__global__ __launch_bounds__(256) void gemm_mfma(
    const _Float16* __restrict__ A,
    const _Float16* __restrict__ Bt,
    const float* __restrict__ bias,
    _Float16* __restrict__ C, int M, int N, int K, int ldc)
{
    __shared__ __align__(16) _Float16 As[128 * 32];
    __shared__ __align__(16) _Float16 Bs[128 * 32];
    const int tid  = threadIdx.x;
    const int lane = tid & 63;
    const int wave = tid >> 6;
    const int brow = blockIdx.y * 128;
    const int bcol = blockIdx.x * 128;

    f32x4 acc[4][4] = {};

    const int wr = (wave >> 1) * 64;
    const int wc = (wave & 1) * 64;
    const int swz = (lane >> 4) ^ ((lane >> 1) & 3);   // read-side swizzled k-chunk

    for (int k0 = 0; k0 < K; k0 += 32) {
        #pragma unroll
        for (int i = 0; i < 2; ++i) {
            int s   = i * 256 + wave * 64 + lane;       // LDS 16B-slot index
            int row = s >> 2;
            int kc  = (s & 3) ^ ((s >> 3) & 3);         // inverse swizzle on source
            gl2lds16(A + (size_t)(brow + row) * K + k0 + kc * 8,
                     &As[(i * 256 + wave * 64) * 8]);
            gl2lds16(Bt + (size_t)(bcol + row) * K + k0 + kc * 8,
                     &Bs[(i * 256 + wave * 64) * 8]);
        }
        __syncthreads();

        h8 af[4], bfr[4];
        #pragma unroll
        for (int m = 0; m < 4; ++m) {
            int row = wr + m * 16 + (lane & 15);
            af[m] = *(const h8*)&As[row * 32 + swz * 8];
        }
        #pragma unroll
        for (int n = 0; n < 4; ++n) {
            int col = wc + n * 16 + (lane & 15);
            bfr[n] = *(const h8*)&Bs[col * 32 + swz * 8];
        }
        #pragma unroll
        for (int m = 0; m < 4; ++m)
            #pragma unroll
            for (int n = 0; n < 4; ++n)
                acc[m][n] = __builtin_amdgcn_mfma_f32_16x16x32_f16(
                    af[m], bfr[n], acc[m][n], 0, 0, 0);
        __syncthreads();
    }

    #pragma unroll
    for (int m = 0; m < 4; ++m) {
        int r0 = brow + wr + m * 16 + (lane >> 4) * 4;
        #pragma unroll
        for (int n = 0; n < 4; ++n) {
            int c = bcol + wc + n * 16 + (lane & 15);
            float bv = bias ? bias[c] : 0.f;
            #pragma unroll
            for (int j = 0; j < 4; ++j) {
                int r = r0 + j;
                if (r < M) C[(size_t)r * ldc + c] = (_Float16)(acc[m][n][j] + bv);
            }
        }
    }
}

// ---------------- one-shot prep: converts, transposes, pads, bias packing ----
__global__ __launch_bounds__(256) void prep_all(
    const float* __restrict__ x,
    const float* __restrict__ Wl1, const float* __restrict__ Wr1,
    const float* __restrict__ Wl2, const float* __restrict__ Wr2,
    const float* __restrict__ We1, const float* __restrict__ We2,
    const float* __restrict__ relations,
    const float* __restrict__ bl1, const float* __restrict__ br1,
    const float* __restrict__ bl2, const float* __restrict__ br2,
    _Float16* __restrict__ xh, _Float16* __restrict__ hh,
    _Float16* __restrict__ Bt1, _Float16* __restrict__ Bt2,
    _Float16* __restrict__ BtE, _Float16* __restrict__ relh,
    float* __restrict__ pb1, float* __restrict__ pb2)
{
    constexpr long SXV   = (long)NN * INF_ / 4;        // float4 converts of x
    constexpr long nXP   = (long)(MPAD - NN) * 128;    // xh pad
    constexpr long nHP   = (long)(MPAD - NN) * 256;    // hh pad
    constexpr long nW1   = 128 * 256;
    constexpr long nW2   = 256 * 512;
    constexpr long nWe1  = 128 * 256;
    constexpr long nWe2  = 128 * 512;
    constexpr long nRel  = (long)NR * 128;
    constexpr long nRelP = (512 - NR) * 128;
    constexpr long TOT = SXV + nXP + nHP + 2 * nW1 + 2 * nW2 + nWe1 + nWe2
                       + nRel + nRelP + 512 + 1024;

    for (long i = (long)blockIdx.x * 256 + threadIdx.x; i < TOT;
         i += (long)gridDim.x * 256) {
        long j = i;
        if (j < SXV) {
            float4 v = ((const float4*)x)[j];
            h4 o = {(_Float16)v.x, (_Float16)v.y, (_Float16)v.z, (_Float16)v.w};
            ((h4*)xh)[j] = o;
            continue;
        }
        j -= SXV;
        if (j < nXP) { xh[(long)NN * 128 + j] = (_Float16)0.f; continue; }
        j -= nXP;
        if (j < nHP) { hh[(long)NN * 256 + j] = (_Float16)0.f; continue; }
        j -= nHP;
        if (j < nW1) { long k = j >> 8, n = j & 255; Bt1[n * 128 + k] = (_Float16)Wl1[j]; continue; }
        j -= nW1;
        if (j < nW1) { long k = j >> 8, n = j & 255; Bt1[(256 + n) * 128 + k] = (_Float16)Wr1[j]; continue; }
        j -= nW1;
        if (j < nW2) { long k = j >> 9, n = j & 511; Bt2[n * 256 + k] = (_Float16)Wl2[j]; continue; }
        j -= nW2;
        if (j < nW2) { long k = j >> 9, n = j & 511; Bt2[(512 + n) * 256 + k] = (_Float16)Wr2[j]; continue; }
        j -= nW2;
        if (j < nWe1) { long k = j >> 8, n = j & 255; BtE[n * 128 + k] = (_Float16)We1[j]; continue; }
        j -= nWe1;
        if (j < nWe2) { long k = j >> 9, n = j & 511; BtE[(256 + n) * 128 + k] = (_Float16)We2[j]; continue; }
        j -= nWe2;
        if (j < nRel) { relh[j] = (_Float16)relations[j]; continue; }
        j -= nRel;
        if (j < nRelP) { relh[nRel + j] = (_Float16)0.f; continue; }
        j -= nRelP;
        if (j < 512) { pb1[j] = (j < 256) ? bl1[j] : br1[j - 256]; continue; }
        j -= 512;
        pb2[j] = (j < 512) ? bl2[j] : br2[j - 512];
    }
}

// ---------------- CSR build ----------------
__global__ void count_deg(const int* __restrict__ dst, int* __restrict__ deg, int E)
{
    int i = blockIdx.x * blockDim.x + threadIdx.x;
    if (i < E) atomicAdd(&deg[dst[i]], 1);
}

__global__ __launch_bounds__(256) void scan_block_sums(
    const int* __restrict__ deg, int* __restrict__ bsum, int n)
{
    __shared__ int s[256];
    int i = blockIdx.x * 256 + threadIdx.x;
    s[threadIdx.x] = (i < n) ? deg[i] : 0;
    __syncthreads();
    for (int o = 128; o > 0; o >>= 1) {
        if (threadIdx.x < o) s[threadIdx.x] += s[threadIdx.x + o];
        __syncthreads();
    }
    if (threadIdx.x == 0) bsum[blockIdx.x] = s[0];
}

__global__ __launch_bounds__(256) void scan_bsums(
    const int* __restrict__ bsum, int* __restrict__ boff, int nb)
{
    __shared__ int s[256];
    int v = (threadIdx.x < nb) ? bsum[threadIdx.x] : 0;
    s[threadIdx.x] = v;
    __syncthreads();
    for (int o = 1; o < 256; o <<= 1) {
        int t = (threadIdx.x >= o) ? s[threadIdx.x - o] : 0;
        __syncthreads();
        s[threadIdx.x] += t;
        __syncthreads();
    }
    if (threadIdx.x < nb) boff[threadIdx.x] = s[threadIdx.x] - v; // exclusive
}

__global__ __launch_bounds__(256) void scan_final(
    const int* __restrict__ deg, const int* __restrict__ boff,
    int* __restrict__ offsets, int n)
{
    __shared__ int s[256];
    int i = blockIdx.x * 256 + threadIdx.x;
    int v = (i < n) ? deg[i] : 0;
    s[threadIdx.x] = v;
    __syncthreads();
    for (int o = 1; o < 256; o <<= 1) {
        int t = (threadIdx.x >= o) ? s[threadIdx.x - o] : 0;
        __syncthreads();
        s[threadIdx.x] += t;
        __syncthreads();
    }
    int incl = s[threadIdx.x];
    int excl = incl - v;
    if (i < n) offsets[i] = boff[blockIdx.x] + excl;
    if (i == n - 1) offsets[n] = boff[blockIdx.x] + incl;
}

__global__ void fill_adj(const int* __restrict__ src, const int* __restrict__ rel,
                         const int* __restrict__ dst, const int* __restrict__ offsets,
                         int* __restrict__ cursor,
                         int* __restrict__ adj_src, int* __restrict__ adj_rel, int E)
{
    int e = blockIdx.x * blockDim.x + threadIdx.x;
    if (e < E) {
        int d = dst[e];
        int p = atomicAdd(&cursor[d], 1);
        int slot = offsets[d] + p;
        adj_src[slot] = src[e];
        adj_rel[slot] = rel[e];
    }
}

// ---------------- fused per-node GATv2 attention (f16 packed) ----------------
template <int CPH, bool CONCAT>
__global__ __launch_bounds__(256) void gat_node(
    const _Float16* __restrict__ xlr,   // [n][2*HC]: [xl | xr]
    const _Float16* __restrict__ erel,  // [NR rows][ldE] relations@We slice
    int ldE,
    const int* __restrict__ adj_src, const int* __restrict__ adj_rel,
    const int* __restrict__ offsets,
    const float* __restrict__ att,      // [HC] f32
    const float* __restrict__ bias,     // CONCAT ? [HC] : [CPH]
    void* __restrict__ out, int n)
{
    constexpr int HC  = NH * CPH;
    constexpr int VPL = HC / 64;
    constexpr int NP  = VPL / 2;
    const int lane = threadIdx.x & 63;
    const int wave = threadIdx.x >> 6;
    const int v = blockIdx.x * 4 + wave;
    if (v >= n) return;

    const _Float16* xlrow = xlr + (size_t)v * (2 * HC) + lane * VPL;
    h2 xl[NP], xr[NP], attp[NP], acc[NP];
    load_h<NP>(xlrow, xl);
    load_h<NP>(xlrow + HC, xr);
    #pragma unroll
    for (int p = 0; p < NP; ++p) {
        attp[p][0] = (_Float16)att[lane * VPL + 2 * p];
        attp[p][1] = (_Float16)att[lane * VPL + 2 * p + 1];
        acc[p] = xl[p];
    }

    // self loop logit
    float pS = 0.f;
    #pragma unroll
    for (int p = 0; p < NP; ++p) pS = fdot2a(lrelu2(xl[p] + xr[p]), attp[p], pS);
    pS += __shfl_xor(pS, 1);
    pS += __shfl_xor(pS, 2);
    pS += __shfl_xor(pS, 4);
    pS += __shfl_xor(pS, 8);
    float m_run = pS, l_run = 1.f;

    const int beg = offsets[v], end = offsets[v + 1];
    int idx = beg;
    for (; idx + 4 <= end; idx += 4) {
        int s0 = adj_src[idx],     s1 = adj_src[idx + 1];
        int s2 = adj_src[idx + 2], s3 = adj_src[idx + 3];
        int r0 = adj_rel[idx],     r1 = adj_rel[idx + 1];
        int r2 = adj_rel[idx + 2], r3 = adj_rel[idx + 3];
        h2 xs0[NP], xs1[NP], xs2[NP], xs3[NP];
        h2 e0[NP], e1[NP], e2[NP], e3[NP];
        load_h<NP>(xlr + (size_t)s0 * (2 * HC) + lane * VPL, xs0);
        load_h<NP>(xlr + (size_t)s1 * (2 * HC) + lane * VPL, xs1);
        load_h<NP>(xlr + (size_t)s2 * (2 * HC) + lane * VPL, xs2);
        load_h<NP>(xlr + (size_t)s3 * (2 * HC) + lane * VPL, xs3);
        load_h<NP>(erel + (size_t)r0 * ldE + lane * VPL, e0);
        load_h<NP>(erel + (size_t)r1 * ldE + lane * VPL, e1);
        load_h<NP>(erel + (size_t)r2 * ldE + lane * VPL, e2);
        load_h<NP>(erel + (size_t)r3 * ldE + lane * VPL, e3);
        float p0 = 0.f, p1 = 0.f, p2 = 0.f, p3 = 0.f;
        #pragma unroll
        for (int p = 0; p < NP; ++p) {
            p0 = fdot2a(lrelu2(xs0[p] + xr[p] + e0[p]), attp[p], p0);
            p1 = fdot2a(lrelu2(xs1[p] + xr[p] + e1[p]), attp[p], p1);
            p2 = fdot2a(lrelu2(xs2[p] + xr[p] + e2[p]), attp[p], p2);
            p3 = fdot2a(lrelu2(xs3[p] + xr[p] + e3[p]), attp[p], p3);
        }
        p0 += __shfl_xor(p0, 1); p1 += __shfl_xor(p1, 1);
        p2 += __shfl_xor(p2, 1); p3 += __shfl_xor(p3, 1);
        p0 += __shfl_xor(p0, 2); p1 += __shfl_xor(p1, 2);
        p2 += __shfl_xor(p2, 2); p3 += __shfl_xor(p3, 2);
        p0 += __shfl_xor(p0, 4); p1 += __shfl_xor(p1, 4);
        p2 += __shfl_xor(p2, 4); p3 += __shfl_xor(p3, 4);
        p0 += __shfl_xor(p0, 8); p1 += __shfl_xor(p1, 8);
        p2 += __shfl_xor(p2, 8); p3 += __shfl_xor(p3, 8);
        float mx = fmaxf(fmaxf(fmaxf(p0, p1), fmaxf(p2, p3)), m_run);
        float sc = __expf(m_run - mx);
        float w0 = __expf(p0 - mx), w1 = __expf(p1 - mx);
        float w2 = __expf(p2 - mx), w3 = __expf(p3 - mx);
        l_run = l_run * sc + ((w0 + w1) + (w2 + w3));
        h2 sc2 = b2(sc), w02 = b2(w0), w12 = b2(w1), w22 = b2(w2), w32 = b2(w3);
        #pragma unroll
        for (int p = 0; p < NP; ++p)
            acc[p] = ((acc[p] * sc2 + xs0[p] * w02) + (xs1[p] * w12 + xs2[p] * w22))
                   + xs3[p] * w32;
        m_run = mx;
    }
    for (; idx < end; ++idx) {
        int s0 = adj_src[idx], r0 = adj_rel[idx];
        h2 xs0[NP], e0[NP];
        load_h<NP>(xlr + (size_t)s0 * (2 * HC) + lane * VPL, xs0);
        load_h<NP>(erel + (size_t)r0 * ldE + lane * VPL, e0);
        float p0 = 0.f;
        #pragma unroll
        for (int p = 0; p < NP; ++p)
            p0 = fdot2a(lrelu2(xs0[p] + xr[p] + e0[p]), attp[p], p0);
        p0 += __shfl_xor(p0, 1);
        p0 += __shfl_xor(p0, 2);
        p0 += __shfl_xor(p0, 4);
        p0 += __shfl_xor(p0, 8);
        float mx = fmaxf(m_run, p0);
        float sc = __expf(m_run - mx);
        float w0 = __expf(p0 - mx);
        l_run = l_run * sc + w0;
        h2 sc2 = b2(sc), w02 = b2(w0);
        #pragma unroll
        for (int p = 0; p < NP; ++p) acc[p] = acc[p] * sc2 + xs0[p] * w02;
        m_run = mx;
    }

    float inv = 1.f / l_run;
    if constexpr (CONCAT) {
        _Float16* ob = (_Float16*)out + (size_t)v * HC + lane * VPL;
        if constexpr (NP == 2) {
            h4 o;
            #pragma unroll
            for (int p = 0; p < NP; ++p) {
                o[2 * p]     = (_Float16)((float)acc[p][0] * inv + bias[lane * VPL + 2 * p]);
                o[2 * p + 1] = (_Float16)((float)acc[p][1] * inv + bias[lane * VPL + 2 * p + 1]);
            }
            *(h4*)ob = o;
        } else {
            h8 o;
            #pragma unroll
            for (int p = 0; p < NP; ++p) {
                o[2 * p]     = (_Float16)((float)acc[p][0] * inv + bias[lane * VPL + 2 * p]);
                o[2 * p + 1] = (_Float16)((float)acc[p][1] * inv + bias[lane * VPL + 2 * p + 1]);
            }
            *(h8*)ob = o;
        }
    } else {
        float* of = (float*)out;
        float t[VPL];
        #pragma unroll
        for (int j = 0; j < VPL; ++j) {
            t[j] = (float)acc[j / 2][j & 1] * inv;
            t[j] += __shfl_xor(t[j], 16);
            t[j] += __shfl_xor(t[j], 32);
        }
        if (lane < 16) {
            #pragma unroll
            for (int j = 0; j < VPL; ++j)
                of[(size_t)v * CPH + lane * VPL + j] = 0.25f * t[j] + bias[lane * VPL + j];
        }
    }
}

// ---------------- host launcher ----------------
extern "C" void kernel_launch(void* const* d_in, const int* in_sizes, int n_in,
                              void* d_out, int out_size, void* d_ws, size_t ws_size,
                              hipStream_t stream)
{
    const float* x         = (const float*)d_in[0];
    const int*   ei        = (const int*)d_in[1];
    const float* relations = (const float*)d_in[2];
    const float* Wl1  = (const float*)d_in[3];
    const float* bl1  = (const float*)d_in[4];
    const float* Wr1  = (const float*)d_in[5];
    const float* br1  = (const float*)d_in[6];
    const float* We1  = (const float*)d_in[7];
    const float* att1 = (const float*)d_in[8];
    const float* bias1= (const float*)d_in[9];
    const float* Wl2  = (const float*)d_in[10];
    const float* bl2  = (const float*)d_in[11];
    const float* Wr2  = (const float*)d_in[12];
    const float* br2  = (const float*)d_in[13];
    const float* We2  = (const float*)d_in[14];
    const float* att2 = (const float*)d_in[15];
    const float* bias2= (const float*)d_in[16];
    float* out = (float*)d_out;

    const int* src = ei;
    const int* rel = ei + NE;
    const int* dst = ei + 2 * NE;

    // ---- workspace layout (f16 = _Float16) ----
    _Float16* xlrh  = (_Float16*)d_ws;                       // NN*1024
    _Float16* xh    = xlrh + (size_t)NN * 1024;              // MPAD*128
    _Float16* hh    = xh + (size_t)MPAD * 128;               // MPAD*256
    _Float16* Bt1   = hh + (size_t)MPAD * 256;               // 512*128
    _Float16* Bt2   = Bt1 + 512 * 128;                       // 1024*256
    _Float16* BtE   = Bt2 + 1024 * 256;                      // 768*128
    _Float16* relh  = BtE + 768 * 128;                       // 512*128
    _Float16* erelC = relh + 512 * 128;                      // 512*768
    float* pb1      = (float*)(erelC + 512 * 768);           // 512
    float* pb2      = pb1 + 512;                             // 1024
    int* deg     = (int*)(pb2 + 1024);
    int* cursor  = deg + NN;
    int* offsets = cursor + NN;       // NN+1
    int* bsum    = offsets + NN + 1;  // 256
    int* boff    = bsum + 256;        // 256
    int* adj_src = boff + 256;        // NE
    int* adj_rel = adj_src + NE;      // NE

    const int NB = (NN + 255) / 256;  // 196
    const int EB = (NE + 255) / 256;

    // --- zero deg+cursor (adjacent) ---
    hipMemsetAsync(deg, 0, (size_t)2 * NN * sizeof(int), stream);

    // --- one-shot prep (converts/transposes/pads/bias packing) ---
    prep_all<<<2048, 256, 0, stream>>>(x, Wl1, Wr1, Wl2, Wr2, We1, We2, relations,
                                       bl1, br1, bl2, br2,
                                       xh, hh, Bt1, Bt2, BtE, relh, pb1, pb2);

    // --- CSR by destination ---
    count_deg<<<EB, 256, 0, stream>>>(dst, deg, NE);
    scan_block_sums<<<NB, 256, 0, stream>>>(deg, bsum, NN);
    scan_bsums<<<1, 256, 0, stream>>>(bsum, boff, NB);
    scan_final<<<NB, 256, 0, stream>>>(deg, boff, offsets, NN);
    fill_adj<<<EB, 256, 0, stream>>>(src, rel, dst, offsets, cursor, adj_src, adj_rel, NE);

    // --- relation tables: erelC[500 x 768] = relations @ [We1 | We2] ---
    gemm_mfma<<<dim3(6, 4), 256, 0, stream>>>(relh, BtE, nullptr, erelC, NR, 768, 128, 768);

    // --- layer 1 transform: xlr1 = [x@Wl1+bl1 | x@Wr1+br1] ---
    gemm_mfma<<<dim3(4, MPAD / 128), 256, 0, stream>>>(xh, Bt1, pb1, xlrh, NN, 512, 128, 512);

    // --- layer 1 attention -> h (f16) ---
    gat_node<HIDC, true><<<(NN + 3) / 4, 256, 0, stream>>>(
        xlrh, erelC, 768, adj_src, adj_rel, offsets, att1, bias1, hh, NN);

    // --- layer 2 transform: xlr2 = [h@Wl2+bl2 | h@Wr2+br2] ---
    gemm_mfma<<<dim3(8, MPAD / 128), 256, 0, stream>>>(hh, Bt2, pb2, xlrh, NN, 1024, 256, 1024);

    // --- layer 2 attention (mean over heads) -> out ---
    gat_node<OUTC, false><<<(NN + 3) / 4, 256, 0, stream>>>(
        xlrh, erelC + 256, 768, adj_src, adj_rel, offsets, att2, bias2, out, NN);
}

// Round 5
// 311.850 us; speedup vs baseline: 3.3347x; 1.0494x over previous
//
#include <hip/hip_runtime.h>
#include <math.h>

constexpr int NN   = 50000;   // nodes
constexpr int NE   = 400000;  // edges
constexpr int NR   = 500;     // relations
constexpr int INF_ = 128;     // input feat
constexpr int HIDC = 64;      // layer1 per-head channels
constexpr int NH   = 4;       // heads
constexpr int OUTC = 128;     // layer2 per-head channels
constexpr int MPAD = 50048;   // 391 * 128

typedef __attribute__((ext_vector_type(2))) _Float16 h2;
typedef __attribute__((ext_vector_type(4))) _Float16 h4;
typedef __attribute__((ext_vector_type(8))) _Float16 h8;
typedef __attribute__((ext_vector_type(4))) float f32x4;

__device__ __forceinline__ h2 b2(float f) {
    _Float16 h = (_Float16)f;
    return (h2){h, h};
}

__device__ __forceinline__ h2 lrelu2(h2 x) {
    h2 t = x * (h2){(_Float16)0.2f, (_Float16)0.2f};
#if __has_builtin(__builtin_elementwise_max)
    return __builtin_elementwise_max(x, t);
#else
    h2 r;
    r[0] = x[0] > t[0] ? x[0] : t[0];
    r[1] = x[1] > t[1] ? x[1] : t[1];
    return r;
#endif
}

__device__ __forceinline__ float fdot2a(h2 a, h2 b, float c) {
#if __has_builtin(__builtin_amdgcn_fdot2)
    return __builtin_amdgcn_fdot2(a, b, c, false);
#else
    return c + (float)a[0] * (float)b[0] + (float)a[1] * (float)b[1];
#endif
}

template <int NP>
__device__ __forceinline__ void load_h(const _Float16* p, h2* d) {
    if constexpr (NP == 2) {
        h4 t = *(const h4*)p;
        d[0] = (h2){t[0], t[1]}; d[1] = (h2){t[2], t[3]};
    } else {
        h8 t = *(const h8*)p;
        d[0] = (h2){t[0], t[1]}; d[1] = (h2){t[2], t[3]};
        d[2] = (h2){t[4], t[5]}; d[3] = (h2){t[6], t[7]};
    }
}

__device__ __forceinline__ void gl2lds16(const void* g, void* l) {
    __builtin_amdgcn_global_load_lds(
        (const __attribute__((address_space(1))) unsigned int*)g,
        (__attribute__((address_space(3))) unsigned int*)l, 16, 0, 0);
}

// ---------------- MFMA f16 GEMM, double-buffered + counted vmcnt ----------------
// C[M x N](f16, stride ldc) = A[* x K](f16) @ Bt[N x K](f16)^T + bias[N]
// 128x128 tile, BK=32, 4 waves (2x2 of 64x64), global_load_lds staging,
// XOR swizzle on 16B chunks (<=2-way LDS conflict = free).
// 2-phase pipeline: STAGE(t+1) issued before compute(t); s_waitcnt vmcnt(4)
// keeps next tile's 4 loads in flight across the raw s_barrier (T3/T4).
// Bijective XCD-chunked swizzle (m204): all N-blocks of one A-panel -> one XCD.
__global__ __launch_bounds__(256) void gemm_mfma(
    const _Float16* __restrict__ A,
    const _Float16* __restrict__ Bt,
    const float* __restrict__ bias,
    _Float16* __restrict__ C, int M, int N, int K, int ldc, int ntn)
{
    __shared__ __align__(16) _Float16 As[2][128 * 32];
    __shared__ __align__(16) _Float16 Bs[2][128 * 32];
    const int tid  = threadIdx.x;
    const int lane = tid & 63;
    const int wave = tid >> 6;

    // bijective XCD-chunked swizzle
    const int nwg = gridDim.x;
    const int q = nwg >> 3, r = nwg & 7;
    const int xcd = blockIdx.x & 7, jj = blockIdx.x >> 3;
    const int swid = (xcd < r ? xcd * (q + 1) : r * (q + 1) + (xcd - r) * q) + jj;
    const int brow = (swid / ntn) * 128;
    const int bcol = (swid % ntn) * 128;

    f32x4 acc[4][4] = {};
    const int wr = (wave >> 1) * 64;
    const int wc = (wave & 1) * 64;
    const int swz = (lane >> 4) ^ ((lane >> 1) & 3);   // read-side swizzled k-chunk

    // staging addresses (slot s = i*256 + wave*64 + lane; 16B per slot)
    const int s0 = wave * 64 + lane;
    const int s1 = 256 + wave * 64 + lane;
    const int row0 = s0 >> 2, kc0 = (s0 & 3) ^ ((s0 >> 3) & 3);
    const int row1 = s1 >> 2, kc1 = (s1 & 3) ^ ((s1 >> 3) & 3);
    const _Float16* a0 = A + (size_t)(brow + row0) * K + kc0 * 8;
    const _Float16* a1 = A + (size_t)(brow + row1) * K + kc1 * 8;
    const _Float16* b0 = Bt + (size_t)(bcol + row0) * K + kc0 * 8;
    const _Float16* b1 = Bt + (size_t)(bcol + row1) * K + kc1 * 8;

#define STAGE(buf, k0) do {                                   \
        gl2lds16(a0 + (k0), &As[buf][wave * 512]);            \
        gl2lds16(b0 + (k0), &Bs[buf][wave * 512]);            \
        gl2lds16(a1 + (k0), &As[buf][2048 + wave * 512]);     \
        gl2lds16(b1 + (k0), &Bs[buf][2048 + wave * 512]);     \
    } while (0)

    STAGE(0, 0);
    const int nt = K >> 5;
    int cur = 0;
    for (int t = 0; t < nt; ++t) {
        if (t + 1 < nt) {
            STAGE(cur ^ 1, (t + 1) * 32);
            asm volatile("s_waitcnt vmcnt(4)" ::: "memory");   // current tile landed; next stays in flight
        } else {
            asm volatile("s_waitcnt vmcnt(0)" ::: "memory");
        }
        __builtin_amdgcn_s_barrier();
        __builtin_amdgcn_sched_barrier(0);                     // keep ds_reads below the barrier
        h8 af[4], bfr[4];
        #pragma unroll
        for (int m = 0; m < 4; ++m)
            af[m] = *(const h8*)&As[cur][(wr + m * 16 + (lane & 15)) * 32 + swz * 8];
        #pragma unroll
        for (int n = 0; n < 4; ++n)
            bfr[n] = *(const h8*)&Bs[cur][(wc + n * 16 + (lane & 15)) * 32 + swz * 8];
        #pragma unroll
        for (int m = 0; m < 4; ++m)
            #pragma unroll
            for (int n = 0; n < 4; ++n)
                acc[m][n] = __builtin_amdgcn_mfma_f32_16x16x32_f16(
                    af[m], bfr[n], acc[m][n], 0, 0, 0);
        __builtin_amdgcn_s_barrier();                          // reads of buf[cur] done -> overwritable
        cur ^= 1;
    }
#undef STAGE

    #pragma unroll
    for (int m = 0; m < 4; ++m) {
        int r0 = brow + wr + m * 16 + (lane >> 4) * 4;
        #pragma unroll
        for (int n = 0; n < 4; ++n) {
            int c = bcol + wc + n * 16 + (lane & 15);
            float bv = bias ? bias[c] : 0.f;
            #pragma unroll
            for (int j = 0; j < 4; ++j) {
                int rr = r0 + j;
                if (rr < M) C[(size_t)rr * ldc + c] = (_Float16)(acc[m][n][j] + bv);
            }
        }
    }
}

// ---------------- one-shot prep: converts, transposes, pads, bias packing ----
__global__ __launch_bounds__(256) void prep_all(
    const float* __restrict__ x,
    const float* __restrict__ Wl1, const float* __restrict__ Wr1,
    const float* __restrict__ Wl2, const float* __restrict__ Wr2,
    const float* __restrict__ We1, const float* __restrict__ We2,
    const float* __restrict__ relations,
    const float* __restrict__ bl1, const float* __restrict__ br1,
    const float* __restrict__ bl2, const float* __restrict__ br2,
    _Float16* __restrict__ xh, _Float16* __restrict__ hh,
    _Float16* __restrict__ Bt1, _Float16* __restrict__ Bt2,
    _Float16* __restrict__ BtE, _Float16* __restrict__ relh,
    float* __restrict__ pb1, float* __restrict__ pb2)
{
    constexpr long SXV   = (long)NN * INF_ / 4;        // float4 converts of x
    constexpr long nXP   = (long)(MPAD - NN) * 128;    // xh pad
    constexpr long nHP   = (long)(MPAD - NN) * 256;    // hh pad
    constexpr long nW1   = 128 * 256;
    constexpr long nW2   = 256 * 512;
    constexpr long nWe1  = 128 * 256;
    constexpr long nWe2  = 128 * 512;
    constexpr long nRel  = (long)NR * 128;
    constexpr long nRelP = (512 - NR) * 128;
    constexpr long TOT = SXV + nXP + nHP + 2 * nW1 + 2 * nW2 + nWe1 + nWe2
                       + nRel + nRelP + 512 + 1024;

    for (long i = (long)blockIdx.x * 256 + threadIdx.x; i < TOT;
         i += (long)gridDim.x * 256) {
        long j = i;
        if (j < SXV) {
            float4 v = ((const float4*)x)[j];
            h4 o = {(_Float16)v.x, (_Float16)v.y, (_Float16)v.z, (_Float16)v.w};
            ((h4*)xh)[j] = o;
            continue;
        }
        j -= SXV;
        if (j < nXP) { xh[(long)NN * 128 + j] = (_Float16)0.f; continue; }
        j -= nXP;
        if (j < nHP) { hh[(long)NN * 256 + j] = (_Float16)0.f; continue; }
        j -= nHP;
        if (j < nW1) { long k = j >> 8, n = j & 255; Bt1[n * 128 + k] = (_Float16)Wl1[j]; continue; }
        j -= nW1;
        if (j < nW1) { long k = j >> 8, n = j & 255; Bt1[(256 + n) * 128 + k] = (_Float16)Wr1[j]; continue; }
        j -= nW1;
        if (j < nW2) { long k = j >> 9, n = j & 511; Bt2[n * 256 + k] = (_Float16)Wl2[j]; continue; }
        j -= nW2;
        if (j < nW2) { long k = j >> 9, n = j & 511; Bt2[(512 + n) * 256 + k] = (_Float16)Wr2[j]; continue; }
        j -= nW2;
        if (j < nWe1) { long k = j >> 8, n = j & 255; BtE[n * 128 + k] = (_Float16)We1[j]; continue; }
        j -= nWe1;
        if (j < nWe2) { long k = j >> 9, n = j & 511; BtE[(256 + n) * 128 + k] = (_Float16)We2[j]; continue; }
        j -= nWe2;
        if (j < nRel) { relh[j] = (_Float16)relations[j]; continue; }
        j -= nRel;
        if (j < nRelP) { relh[nRel + j] = (_Float16)0.f; continue; }
        j -= nRelP;
        if (j < 512) { pb1[j] = (j < 256) ? bl1[j] : br1[j - 256]; continue; }
        j -= 512;
        pb2[j] = (j < 512) ? bl2[j] : br2[j - 512];
    }
}

// ---------------- CSR build ----------------
__global__ void count_deg(const int* __restrict__ dst, int* __restrict__ deg, int E)
{
    int i = blockIdx.x * blockDim.x + threadIdx.x;
    if (i < E) atomicAdd(&deg[dst[i]], 1);
}

__global__ __launch_bounds__(256) void scan_block_sums(
    const int* __restrict__ deg, int* __restrict__ bsum, int n)
{
    __shared__ int s[256];
    int i = blockIdx.x * 256 + threadIdx.x;
    s[threadIdx.x] = (i < n) ? deg[i] : 0;
    __syncthreads();
    for (int o = 128; o > 0; o >>= 1) {
        if (threadIdx.x < o) s[threadIdx.x] += s[threadIdx.x + o];
        __syncthreads();
    }
    if (threadIdx.x == 0) bsum[blockIdx.x] = s[0];
}

__global__ __launch_bounds__(256) void scan_bsums(
    const int* __restrict__ bsum, int* __restrict__ boff, int nb)
{
    __shared__ int s[256];
    int v = (threadIdx.x < nb) ? bsum[threadIdx.x] : 0;
    s[threadIdx.x] = v;
    __syncthreads();
    for (int o = 1; o < 256; o <<= 1) {
        int t = (threadIdx.x >= o) ? s[threadIdx.x - o] : 0;
        __syncthreads();
        s[threadIdx.x] += t;
        __syncthreads();
    }
    if (threadIdx.x < nb) boff[threadIdx.x] = s[threadIdx.x] - v; // exclusive
}

__global__ __launch_bounds__(256) void scan_final(
    const int* __restrict__ deg, const int* __restrict__ boff,
    int* __restrict__ offsets, int n)
{
    __shared__ int s[256];
    int i = blockIdx.x * 256 + threadIdx.x;
    int v = (i < n) ? deg[i] : 0;
    s[threadIdx.x] = v;
    __syncthreads();
    for (int o = 1; o < 256; o <<= 1) {
        int t = (threadIdx.x >= o) ? s[threadIdx.x - o] : 0;
        __syncthreads();
        s[threadIdx.x] += t;
        __syncthreads();
    }
    int incl = s[threadIdx.x];
    int excl = incl - v;
    if (i < n) offsets[i] = boff[blockIdx.x] + excl;
    if (i == n - 1) offsets[n] = boff[blockIdx.x] + incl;
}

__global__ void fill_adj(const int* __restrict__ src, const int* __restrict__ rel,
                         const int* __restrict__ dst, const int* __restrict__ offsets,
                         int* __restrict__ cursor,
                         int* __restrict__ adj_src, int* __restrict__ adj_rel, int E)
{
    int e = blockIdx.x * blockDim.x + threadIdx.x;
    if (e < E) {
        int d = dst[e];
        int p = atomicAdd(&cursor[d], 1);
        int slot = offsets[d] + p;
        adj_src[slot] = src[e];
        adj_rel[slot] = rel[e];
    }
}

// ---------------- fused per-node GATv2 attention (f16 packed) ----------------
template <int CPH, bool CONCAT>
__global__ __launch_bounds__(256) void gat_node(
    const _Float16* __restrict__ xlr,   // [n][2*HC]: [xl | xr]
    const _Float16* __restrict__ erel,  // [NR rows][ldE] relations@We slice
    int ldE,
    const int* __restrict__ adj_src, const int* __restrict__ adj_rel,
    const int* __restrict__ offsets,
    const float* __restrict__ att,      // [HC] f32
    const float* __restrict__ bias,     // CONCAT ? [HC] : [CPH]
    void* __restrict__ out, int n)
{
    constexpr int HC  = NH * CPH;
    constexpr int VPL = HC / 64;
    constexpr int NP  = VPL / 2;
    const int lane = threadIdx.x & 63;
    const int wave = threadIdx.x >> 6;
    const int v = blockIdx.x * 4 + wave;
    if (v >= n) return;

    const _Float16* xlrow = xlr + (size_t)v * (2 * HC) + lane * VPL;
    h2 xl[NP], xr[NP], attp[NP], acc[NP];
    load_h<NP>(xlrow, xl);
    load_h<NP>(xlrow + HC, xr);
    #pragma unroll
    for (int p = 0; p < NP; ++p) {
        attp[p][0] = (_Float16)att[lane * VPL + 2 * p];
        attp[p][1] = (_Float16)att[lane * VPL + 2 * p + 1];
        acc[p] = xl[p];
    }

    // self loop logit
    float pS = 0.f;
    #pragma unroll
    for (int p = 0; p < NP; ++p) pS = fdot2a(lrelu2(xl[p] + xr[p]), attp[p], pS);
    pS += __shfl_xor(pS, 1);
    pS += __shfl_xor(pS, 2);
    pS += __shfl_xor(pS, 4);
    pS += __shfl_xor(pS, 8);
    float m_run = pS, l_run = 1.f;

    const int beg = offsets[v], end = offsets[v + 1];
    int idx = beg;
    for (; idx + 4 <= end; idx += 4) {
        int s0 = adj_src[idx],     s1 = adj_src[idx + 1];
        int s2 = adj_src[idx + 2], s3 = adj_src[idx + 3];
        int r0 = adj_rel[idx],     r1 = adj_rel[idx + 1];
        int r2 = adj_rel[idx + 2], r3 = adj_rel[idx + 3];
        h2 xs0[NP], xs1[NP], xs2[NP], xs3[NP];
        h2 e0[NP], e1[NP], e2[NP], e3[NP];
        load_h<NP>(xlr + (size_t)s0 * (2 * HC) + lane * VPL, xs0);
        load_h<NP>(xlr + (size_t)s1 * (2 * HC) + lane * VPL, xs1);
        load_h<NP>(xlr + (size_t)s2 * (2 * HC) + lane * VPL, xs2);
        load_h<NP>(xlr + (size_t)s3 * (2 * HC) + lane * VPL, xs3);
        load_h<NP>(erel + (size_t)r0 * ldE + lane * VPL, e0);
        load_h<NP>(erel + (size_t)r1 * ldE + lane * VPL, e1);
        load_h<NP>(erel + (size_t)r2 * ldE + lane * VPL, e2);
        load_h<NP>(erel + (size_t)r3 * ldE + lane * VPL, e3);
        float p0 = 0.f, p1 = 0.f, p2 = 0.f, p3 = 0.f;
        #pragma unroll
        for (int p = 0; p < NP; ++p) {
            p0 = fdot2a(lrelu2(xs0[p] + xr[p] + e0[p]), attp[p], p0);
            p1 = fdot2a(lrelu2(xs1[p] + xr[p] + e1[p]), attp[p], p1);
            p2 = fdot2a(lrelu2(xs2[p] + xr[p] + e2[p]), attp[p], p2);
            p3 = fdot2a(lrelu2(xs3[p] + xr[p] + e3[p]), attp[p], p3);
        }
        p0 += __shfl_xor(p0, 1); p1 += __shfl_xor(p1, 1);
        p2 += __shfl_xor(p2, 1); p3 += __shfl_xor(p3, 1);
        p0 += __shfl_xor(p0, 2); p1 += __shfl_xor(p1, 2);
        p2 += __shfl_xor(p2, 2); p3 += __shfl_xor(p3, 2);
        p0 += __shfl_xor(p0, 4); p1 += __shfl_xor(p1, 4);
        p2 += __shfl_xor(p2, 4); p3 += __shfl_xor(p3, 4);
        p0 += __shfl_xor(p0, 8); p1 += __shfl_xor(p1, 8);
        p2 += __shfl_xor(p2, 8); p3 += __shfl_xor(p3, 8);
        float mx = fmaxf(fmaxf(fmaxf(p0, p1), fmaxf(p2, p3)), m_run);
        float sc = __expf(m_run - mx);
        float w0 = __expf(p0 - mx), w1 = __expf(p1 - mx);
        float w2 = __expf(p2 - mx), w3 = __expf(p3 - mx);
        l_run = l_run * sc + ((w0 + w1) + (w2 + w3));
        h2 sc2 = b2(sc), w02 = b2(w0), w12 = b2(w1), w22 = b2(w2), w32 = b2(w3);
        #pragma unroll
        for (int p = 0; p < NP; ++p)
            acc[p] = ((acc[p] * sc2 + xs0[p] * w02) + (xs1[p] * w12 + xs2[p] * w22))
                   + xs3[p] * w32;
        m_run = mx;
    }
    for (; idx < end; ++idx) {
        int s0 = adj_src[idx], r0 = adj_rel[idx];
        h2 xs0[NP], e0[NP];
        load_h<NP>(xlr + (size_t)s0 * (2 * HC) + lane * VPL, xs0);
        load_h<NP>(erel + (size_t)r0 * ldE + lane * VPL, e0);
        float p0 = 0.f;
        #pragma unroll
        for (int p = 0; p < NP; ++p)
            p0 = fdot2a(lrelu2(xs0[p] + xr[p] + e0[p]), attp[p], p0);
        p0 += __shfl_xor(p0, 1);
        p0 += __shfl_xor(p0, 2);
        p0 += __shfl_xor(p0, 4);
        p0 += __shfl_xor(p0, 8);
        float mx = fmaxf(m_run, p0);
        float sc = __expf(m_run - mx);
        float w0 = __expf(p0 - mx);
        l_run = l_run * sc + w0;
        h2 sc2 = b2(sc), w02 = b2(w0);
        #pragma unroll
        for (int p = 0; p < NP; ++p) acc[p] = acc[p] * sc2 + xs0[p] * w02;
        m_run = mx;
    }

    float inv = 1.f / l_run;
    if constexpr (CONCAT) {
        _Float16* ob = (_Float16*)out + (size_t)v * HC + lane * VPL;
        if constexpr (NP == 2) {
            h4 o;
            #pragma unroll
            for (int p = 0; p < NP; ++p) {
                o[2 * p]     = (_Float16)((float)acc[p][0] * inv + bias[lane * VPL + 2 * p]);
                o[2 * p + 1] = (_Float16)((float)acc[p][1] * inv + bias[lane * VPL + 2 * p + 1]);
            }
            *(h4*)ob = o;
        } else {
            h8 o;
            #pragma unroll
            for (int p = 0; p < NP; ++p) {
                o[2 * p]     = (_Float16)((float)acc[p][0] * inv + bias[lane * VPL + 2 * p]);
                o[2 * p + 1] = (_Float16)((float)acc[p][1] * inv + bias[lane * VPL + 2 * p + 1]);
            }
            *(h8*)ob = o;
        }
    } else {
        float* of = (float*)out;
        float t[VPL];
        #pragma unroll
        for (int j = 0; j < VPL; ++j) {
            t[j] = (float)acc[j / 2][j & 1] * inv;
            t[j] += __shfl_xor(t[j], 16);
            t[j] += __shfl_xor(t[j], 32);
        }
        if (lane < 16) {
            #pragma unroll
            for (int j = 0; j < VPL; ++j)
                of[(size_t)v * CPH + lane * VPL + j] = 0.25f * t[j] + bias[lane * VPL + j];
        }
    }
}

// ---------------- host launcher ----------------
extern "C" void kernel_launch(void* const* d_in, const int* in_sizes, int n_in,
                              void* d_out, int out_size, void* d_ws, size_t ws_size,
                              hipStream_t stream)
{
    const float* x         = (const float*)d_in[0];
    const int*   ei        = (const int*)d_in[1];
    const float* relations = (const float*)d_in[2];
    const float* Wl1  = (const float*)d_in[3];
    const float* bl1  = (const float*)d_in[4];
    const float* Wr1  = (const float*)d_in[5];
    const float* br1  = (const float*)d_in[6];
    const float* We1  = (const float*)d_in[7];
    const float* att1 = (const float*)d_in[8];
    const float* bias1= (const float*)d_in[9];
    const float* Wl2  = (const float*)d_in[10];
    const float* bl2  = (const float*)d_in[11];
    const float* Wr2  = (const float*)d_in[12];
    const float* br2  = (const float*)d_in[13];
    const float* We2  = (const float*)d_in[14];
    const float* att2 = (const float*)d_in[15];
    const float* bias2= (const float*)d_in[16];
    float* out = (float*)d_out;

    const int* src = ei;
    const int* rel = ei + NE;
    const int* dst = ei + 2 * NE;

    // ---- workspace layout (f16 = _Float16) ----
    _Float16* xlrh  = (_Float16*)d_ws;                       // NN*1024
    _Float16* xh    = xlrh + (size_t)NN * 1024;              // MPAD*128
    _Float16* hh    = xh + (size_t)MPAD * 128;               // MPAD*256
    _Float16* Bt1   = hh + (size_t)MPAD * 256;               // 512*128
    _Float16* Bt2   = Bt1 + 512 * 128;                       // 1024*256
    _Float16* BtE   = Bt2 + 1024 * 256;                      // 768*128
    _Float16* relh  = BtE + 768 * 128;                       // 512*128
    _Float16* erelC = relh + 512 * 128;                      // 512*768
    float* pb1      = (float*)(erelC + 512 * 768);           // 512
    float* pb2      = pb1 + 512;                             // 1024
    int* deg     = (int*)(pb2 + 1024);
    int* cursor  = deg + NN;
    int* offsets = cursor + NN;       // NN+1
    int* bsum    = offsets + NN + 1;  // 256
    int* boff    = bsum + 256;        // 256
    int* adj_src = boff + 256;        // NE
    int* adj_rel = adj_src + NE;      // NE

    const int NB = (NN + 255) / 256;  // 196
    const int EB = (NE + 255) / 256;

    // --- zero deg+cursor (adjacent) ---
    hipMemsetAsync(deg, 0, (size_t)2 * NN * sizeof(int), stream);

    // --- one-shot prep (converts/transposes/pads/bias packing) ---
    prep_all<<<2048, 256, 0, stream>>>(x, Wl1, Wr1, Wl2, Wr2, We1, We2, relations,
                                       bl1, br1, bl2, br2,
                                       xh, hh, Bt1, Bt2, BtE, relh, pb1, pb2);

    // --- CSR by destination ---
    count_deg<<<EB, 256, 0, stream>>>(dst, deg, NE);
    scan_block_sums<<<NB, 256, 0, stream>>>(deg, bsum, NN);
    scan_bsums<<<1, 256, 0, stream>>>(bsum, boff, NB);
    scan_final<<<NB, 256, 0, stream>>>(deg, boff, offsets, NN);
    fill_adj<<<EB, 256, 0, stream>>>(src, rel, dst, offsets, cursor, adj_src, adj_rel, NE);

    // --- relation tables: erelC[500 x 768] = relations @ [We1 | We2] ---
    gemm_mfma<<<4 * 6, 256, 0, stream>>>(relh, BtE, nullptr, erelC, NR, 768, 128, 768, 6);

    // --- layer 1 transform: xlr1 = [x@Wl1+bl1 | x@Wr1+br1] ---
    gemm_mfma<<<(MPAD / 128) * 4, 256, 0, stream>>>(xh, Bt1, pb1, xlrh, NN, 512, 128, 512, 4);

    // --- layer 1 attention -> h (f16) ---
    gat_node<HIDC, true><<<(NN + 3) / 4, 256, 0, stream>>>(
        xlrh, erelC, 768, adj_src, adj_rel, offsets, att1, bias1, hh, NN);

    // --- layer 2 transform: xlr2 = [h@Wl2+bl2 | h@Wr2+br2] ---
    gemm_mfma<<<(MPAD / 128) * 8, 256, 0, stream>>>(hh, Bt2, pb2, xlrh, NN, 1024, 256, 1024, 8);

    // --- layer 2 attention (mean over heads) -> out ---
    gat_node<OUTC, false><<<(NN + 3) / 4, 256, 0, stream>>>(
        xlrh, erelC + 256, 768, adj_src, adj_rel, offsets, att2, bias2, out, NN);
}